// Round 1
// baseline (585.192 us; speedup 1.0000x reference)
//
#include <hip/hip_runtime.h>
#include <hip/hip_bf16.h>

typedef __attribute__((ext_vector_type(8))) short bf16x8;
typedef __attribute__((ext_vector_type(4))) float f32x4;
typedef __attribute__((ext_vector_type(4))) _Float16 f16x4;
typedef __attribute__((ext_vector_type(8))) _Float16 f16x8;
typedef __attribute__((ext_vector_type(4))) unsigned short u16x4;

#define B_ 2
#define S_ 2048
#define E_ 2048
#define H_ 16
#define D_ 128
#define ELEMS (B_*S_*E_)   // 8388608 elements of [B,S,2048]
#define WELEMS (E_*E_)     // 4194304 elements per weight matrix

__device__ __forceinline__ unsigned short f2bf(float x) {
  unsigned int u = __float_as_uint(x);
  u += 0x7fffu + ((u >> 16) & 1u);
  return (unsigned short)(u >> 16);
}

__device__ __forceinline__ void async_load16(const void* g, void* l) {
  __builtin_amdgcn_global_load_lds(
      (const __attribute__((address_space(1))) unsigned int*)g,
      (__attribute__((address_space(3))) unsigned int*)l, 16, 0, 0);
}

// f32 -> bf16 (RNE), vectorized x4. n4 = n/4.
__global__ __launch_bounds__(256)
void cvt_f32_bf16(const float* __restrict__ src, unsigned short* __restrict__ dst, int n4)
{
  const int i = blockIdx.x * 256 + threadIdx.x;
  if (i < n4) {
    const f32x4 v = ((const f32x4*)src)[i];
    u16x4 o;
    o.x = f2bf(v.x); o.y = f2bf(v.y); o.z = f2bf(v.z); o.w = f2bf(v.w);
    ((u16x4*)dst)[i] = o;
  }
}

// four equally-sized weight tensors in one launch (blockIdx.y selects)
__global__ __launch_bounds__(256)
void cvt4_f32_bf16(const float* __restrict__ s0, const float* __restrict__ s1,
                   const float* __restrict__ s2, const float* __restrict__ s3,
                   unsigned short* __restrict__ d0, unsigned short* __restrict__ d1,
                   unsigned short* __restrict__ d2, unsigned short* __restrict__ d3,
                   int n4)
{
  const int i = blockIdx.x * 256 + threadIdx.x;
  if (i >= n4) return;
  const float* s; unsigned short* d;
  switch (blockIdx.y) {
    case 0: s = s0; d = d0; break;
    case 1: s = s1; d = d1; break;
    case 2: s = s2; d = d2; break;
    default: s = s3; d = d3; break;
  }
  const f32x4 v = ((const f32x4*)s)[i];
  u16x4 o;
  o.x = f2bf(v.x); o.y = f2bf(v.y); o.z = f2bf(v.z); o.w = f2bf(v.w);
  ((u16x4*)d)[i] = o;
}

// C[m][n] = sum_k A[m][k] * Bw[n][k]   (torch Linear / B^T layout), bf16 in,
// f32 accumulate. OUTMODE: 0 = bf16 row-major, 1 = f32 row-major,
// 2 = bf16 head-major [b, h, s, d] (row=b*2048+s, col=h*128+d),
// 3 = fused-QKV head-major: col in [0, 3*2048); tensor = col>>11 selects
//     Q/K/V (contiguous, ELEMS apart), then head-major like mode 2.
template<int OUTMODE>
__global__ __launch_bounds__(256)
void gemm_bt(const __hip_bfloat16* __restrict__ A,
             const __hip_bfloat16* __restrict__ Bw,
             void* __restrict__ C, int M, int N, int K)
{
  __shared__ __hip_bfloat16 As[128*32];
  __shared__ __hip_bfloat16 Bs[128*32];
  const int tid  = threadIdx.x;
  const int lane = tid & 63;
  const int w    = tid >> 6;
  const int m0 = blockIdx.y * 128;
  const int n0 = blockIdx.x * 128;
  const int wm = (w >> 1) * 64;
  const int wn = (w & 1) * 64;
  const int lrow = lane >> 2;
  const int lcol = (lane & 3) * 8;
  const int fr = lane & 15;
  const int fg = lane >> 4;

  f32x4 acc[4][4];
#pragma unroll
  for (int i = 0; i < 4; i++)
#pragma unroll
    for (int j = 0; j < 4; j++) acc[i][j] = (f32x4)0.0f;

  for (int k0 = 0; k0 < K; k0 += 32) {
    __syncthreads();
#pragma unroll
    for (int s = 0; s < 2; s++) {
      const int rbase = s*64 + w*16;
      async_load16(A  + (size_t)(m0 + rbase + lrow)*K + k0 + lcol, As + rbase*32);
      async_load16(Bw + (size_t)(n0 + rbase + lrow)*K + k0 + lcol, Bs + rbase*32);
    }
    __syncthreads();
    bf16x8 af[4], bfr[4];
#pragma unroll
    for (int i = 0; i < 4; i++) {
      af[i]  = *(const bf16x8*)(As + (wm + i*16 + fr)*32 + fg*8);
      bfr[i] = *(const bf16x8*)(Bs + (wn + i*16 + fr)*32 + fg*8);
    }
#pragma unroll
    for (int i = 0; i < 4; i++)
#pragma unroll
      for (int j = 0; j < 4; j++)
        acc[i][j] = __builtin_amdgcn_mfma_f32_16x16x32_bf16(af[i], bfr[j], acc[i][j], 0, 0, 0);
  }

#pragma unroll
  for (int i = 0; i < 4; i++) {
    const int row = m0 + wm + i*16 + fg*4;
#pragma unroll
    for (int j = 0; j < 4; j++) {
      const int col = n0 + wn + j*16 + fr;
#pragma unroll
      for (int r = 0; r < 4; r++) {
        if (OUTMODE == 1) {
          ((float*)C)[(size_t)(row + r)*N + col] = acc[i][j][r];
        } else if (OUTMODE == 0) {
          ((unsigned short*)C)[(size_t)(row + r)*N + col] = f2bf(acc[i][j][r]);
        } else if (OUTMODE == 2) {
          const int rr = row + r;
          const int b = rr >> 11, s = rr & 2047;
          const int h = col >> 7, d = col & 127;
          ((unsigned short*)C)[(((size_t)(b*H_ + h) << 11) + s)*D_ + d] = f2bf(acc[i][j][r]);
        } else {   // OUTMODE == 3: fused QKV, outputs contiguous ELEMS apart
          const int rr = row + r;
          const int b = rr >> 11, s = rr & 2047;
          const int t = col >> 11;             // 0=Q 1=K 2=V
          const int h = (col >> 7) & 15, d = col & 127;
          ((unsigned short*)C)[(size_t)t*ELEMS +
              (((size_t)(b*H_ + h) << 11) + s)*D_ + d] = f2bf(acc[i][j][r]);
        }
      }
    }
  }
}

// xpos rotary, in place on head-major bf16 Q and K [b,h,s,d].
__global__ __launch_bounds__(256)
void xpos_rotary(__hip_bfloat16* __restrict__ Q, __hip_bfloat16* __restrict__ Kt)
{
  const int idx = blockIdx.x * 256 + threadIdx.x;   // [0, B*H*S*64)
  const int j = idx & 63;
  const int s = (idx >> 6) & 2047;
  const float seq = (float)(s - 1024) * (1.0f/512.0f);
  const float dr = 2.0f + 2.0f*(float)j;
  const float theta = expf(dr * (1.0f/128.0f) * -9.210340371976184f);
  const float zeta  = (dr * (1.0f/64.0f) + 51.2f) * (1.0f/52.2f);
  const float ang = seq * theta;
  const float c  = cosf(ang);
  const float sn = sinf(ang);
  const float t  = expf(seq * logf(zeta));
  const float it = 1.0f / t;

  const size_t base = (size_t)(idx >> 6) * 128 + 2*j;
  unsigned short* Qs = (unsigned short*)Q;
  unsigned short* Ks = (unsigned short*)Kt;
  const float q0 = __bfloat162float(Q[base]),  q1 = __bfloat162float(Q[base+1]);
  Qs[base]   = f2bf((q0*c - q1*sn) * t);
  Qs[base+1] = f2bf((q1*c + q0*sn) * t);
  const float k0 = __bfloat162float(Kt[base]), k1 = __bfloat162float(Kt[base+1]);
  Ks[base]   = f2bf((k0*c - k1*sn) * it);
  Ks[base+1] = f2bf((k1*c + k0*sn) * it);
}

// Vh [b,h,s,d] bf16 -> VT3 packed f16:
// per (bh, kt=s/64) 16-KB tile, inner offset = d*64 + g*16 + half*8 + s1*4 + r
// where key=s%64 = (half*2+s1)*16 + g*4 + r.
__global__ __launch_bounds__(256)
void transpose_v(const __hip_bfloat16* __restrict__ Vh, _Float16* __restrict__ VT3)
{
  __shared__ float tile[32][33];
  const int tx = threadIdx.x, ty = threadIdx.y;      // block (32, 8)
  const int bh = blockIdx.z;
  const int s0 = blockIdx.x * 32, d0 = blockIdx.y * 32;
  const int kt = s0 >> 6, koff = s0 & 63;
#pragma unroll
  for (int r = 0; r < 4; r++) {
    const int s = s0 + ty + r*8;
    tile[ty + r*8][tx] = __bfloat162float(Vh[((size_t)bh*S_ + s)*D_ + d0 + tx]);
  }
  __syncthreads();
  const int key = koff + tx;
  const int g = (key >> 2) & 3, rr = key & 3, half = (key >> 5) & 1, s1 = (key >> 4) & 1;
  const size_t base = (size_t)bh*S_*D_ + (size_t)kt*8192 + g*16 + half*8 + s1*4 + rr;
#pragma unroll
  for (int r = 0; r < 4; r++) {
    const int d = d0 + ty + r*8;
    VT3[base + d*64] = (_Float16)tile[tx][ty + r*8];
  }
}

// Flash attention, causal. 32-key pair iterations with explicit ping-pong
// register double-buffering (prefetch pair kt+1 during compute of kt) so
// loads overlap compute instead of serializing at HBM latency (R5: 64-VGPR
// schedule -> ~17k cyc/iter). launch_bounds(256,2) allows ~256 VGPRs.
// XCD pinning: 1-D grid, all 32 q-blocks of one bh on one XCD so K/V stay
// L2-resident (per-XCD hot set 4 bh x 1 MB = 4 MB = L2 size).
__global__ __launch_bounds__(256, 2)
void attn_fwd(const __hip_bfloat16* __restrict__ Qh,
              const __hip_bfloat16* __restrict__ Kh,
              const _Float16* __restrict__ VT3,
              __hip_bfloat16* __restrict__ O)
{
  __shared__ float smem_f[64*132];     // padded stride 132: no 16-way conflicts
  const int lane = threadIdx.x & 63;
  const int w    = threadIdx.x >> 6;
  const int L  = blockIdx.x;                   // 0..1023
  const int bh = (L & 7) + 8*((L >> 3) & 3);   // bh pinned to XCD = bh&7
  const int x  = 31 - (L >> 5);                // longest-first
  const int b = bh >> 4, h = bh & 15;
  const int q0 = x*64 + w*16;
  const int qc = lane & 15;
  const int g  = lane >> 4;
  const int qv = q0 + qc;

  const __hip_bfloat16* Kb = Kh + (size_t)bh*S_*D_;
  const _Float16* vtb = VT3 + (size_t)bh*S_*D_;

  bf16x8 qf[4];
  {
    const __hip_bfloat16* qrow = Qh + ((size_t)bh*S_ + qv)*D_ + g*8;
#pragma unroll
    for (int c = 0; c < 4; c++) qf[c] = *(const bf16x8*)(qrow + c*32);
  }

  f32x4 acc_o[8];
#pragma unroll
  for (int t = 0; t < 8; t++) acc_o[t] = (f32x4)0.0f;
  float m_i = -1e30f, l_i = 0.0f;
  const float scale = 0.08838834764831845f;   // 1/sqrt(128)

  const int nt = x*4 + w + 1;          // 16-key tiles for this wave
  const int np = nt >> 1;              // full 32-key pairs

  // ping-pong register buffers
  bf16x8 ka0[4], kb0[4], ka1[4], kb1[4];
  f16x8  v0[8], v1[8];

#define ISSUE_LOAD(KA, KB, VV, PAIR) do {                                        \
    const __hip_bfloat16* kr_ = Kb + (size_t)((PAIR)*32 + qc)*D_ + g*8;          \
    _Pragma("unroll")                                                            \
    for (int c = 0; c < 4; c++) {                                                \
      KA[c] = *(const bf16x8*)(kr_ + c*32);                                      \
      KB[c] = *(const bf16x8*)(kr_ + 16*D_ + c*32);                              \
    }                                                                            \
    const _Float16* vp_ = vtb + (size_t)((PAIR) >> 1)*8192 + (size_t)qc*64       \
                        + g*16 + ((PAIR) & 1)*8;                                 \
    _Pragma("unroll")                                                            \
    for (int t = 0; t < 8; t++) VV[t] = *(const f16x8*)(vp_ + t*1024);           \
  } while (0)

#define COMPUTE(KA, KB, VV, PAIR) do {                                           \
    const int k0_ = (PAIR)*32;                                                   \
    f32x4 sA = (f32x4)0.0f, sB = (f32x4)0.0f;                                    \
    _Pragma("unroll")                                                            \
    for (int c = 0; c < 4; c++) {                                                \
      sA = __builtin_amdgcn_mfma_f32_16x16x32_bf16(KA[c], qf[c], sA, 0, 0, 0);   \
      sB = __builtin_amdgcn_mfma_f32_16x16x32_bf16(KB[c], qf[c], sB, 0, 0, 0);   \
    }                                                                            \
    float sv[8];                                                                 \
    _Pragma("unroll")                                                            \
    for (int r = 0; r < 4; r++) {                                                \
      sv[r]   = (k0_      + g*4 + r <= qv) ? sA[r]*scale : -1e30f;               \
      sv[4+r] = (k0_ + 16 + g*4 + r <= qv) ? sB[r]*scale : -1e30f;               \
    }                                                                            \
    float mx = sv[0];                                                            \
    _Pragma("unroll")                                                            \
    for (int j = 1; j < 8; j++) mx = fmaxf(mx, sv[j]);                           \
    mx = fmaxf(mx, __shfl_xor(mx, 16));                                          \
    mx = fmaxf(mx, __shfl_xor(mx, 32));                                          \
    const float m_new = fmaxf(m_i, mx);                                          \
    const float alpha = __expf(m_i - m_new);                                     \
    float p[8], ps = 0.0f;                                                       \
    _Pragma("unroll")                                                            \
    for (int j = 0; j < 8; j++) { p[j] = __expf(sv[j] - m_new); ps += p[j]; }    \
    ps += __shfl_xor(ps, 16);                                                    \
    ps += __shfl_xor(ps, 32);                                                    \
    l_i = l_i*alpha + ps;                                                        \
    m_i = m_new;                                                                 \
    f16x4 pA, pB;                                                                \
    _Pragma("unroll")                                                            \
    for (int r = 0; r < 4; r++) { pA[r] = (_Float16)p[r]; pB[r] = (_Float16)p[4+r]; } \
    _Pragma("unroll")                                                            \
    for (int t = 0; t < 8; t++) acc_o[t] *= alpha;                               \
    _Pragma("unroll")                                                            \
    for (int t = 0; t < 8; t++) {                                                \
      const f16x4 vA = __builtin_shufflevector(VV[t], VV[t], 0, 1, 2, 3);        \
      const f16x4 vB = __builtin_shufflevector(VV[t], VV[t], 4, 5, 6, 7);        \
      acc_o[t] = __builtin_amdgcn_mfma_f32_16x16x16f16(vA, pA, acc_o[t], 0, 0, 0); \
      acc_o[t] = __builtin_amdgcn_mfma_f32_16x16x16f16(vB, pB, acc_o[t], 0, 0, 0); \
    }                                                                            \
  } while (0)

  if (np > 0) ISSUE_LOAD(ka0, kb0, v0, 0);
  int kt = 0;
  while (kt + 2 <= np) {
    ISSUE_LOAD(ka1, kb1, v1, kt+1);
    COMPUTE(ka0, kb0, v0, kt);
    if (kt + 2 < np) ISSUE_LOAD(ka0, kb0, v0, kt+2);
    COMPUTE(ka1, kb1, v1, kt+1);
    kt += 2;
  }
  if (kt < np) COMPUTE(ka0, kb0, v0, kt);   // odd-np last pair (already loaded)

  if (nt & 1) {   // tail: single (diagonal) 16-key subtile
    const int st = nt - 1;
    const __hip_bfloat16* kr = Kb + (size_t)(st*16 + qc)*D_ + g*8;
    bf16x8 kf[4];
#pragma unroll
    for (int c = 0; c < 4; c++) kf[c] = *(const bf16x8*)(kr + c*32);
    const _Float16* vp = vtb + (size_t)(st >> 2)*8192 + (size_t)qc*64 + g*16
                       + ((st >> 1) & 1)*8 + (st & 1)*4;
    f16x4 vf[8];
#pragma unroll
    for (int t = 0; t < 8; t++) vf[t] = *(const f16x4*)(vp + t*1024);
    f32x4 sA = (f32x4)0.0f;
#pragma unroll
    for (int c = 0; c < 4; c++)
      sA = __builtin_amdgcn_mfma_f32_16x16x32_bf16(kf[c], qf[c], sA, 0, 0, 0);
    float sv[4];
#pragma unroll
    for (int r = 0; r < 4; r++)
      sv[r] = (st*16 + g*4 + r <= qv) ? sA[r]*scale : -1e30f;
    float mx = fmaxf(fmaxf(sv[0], sv[1]), fmaxf(sv[2], sv[3]));
    mx = fmaxf(mx, __shfl_xor(mx, 16));
    mx = fmaxf(mx, __shfl_xor(mx, 32));
    const float m_new = fmaxf(m_i, mx);
    const float alpha = __expf(m_i - m_new);
    float p[4], ps = 0.0f;
#pragma unroll
    for (int j = 0; j < 4; j++) { p[j] = __expf(sv[j] - m_new); ps += p[j]; }
    ps += __shfl_xor(ps, 16);
    ps += __shfl_xor(ps, 32);
    l_i = l_i*alpha + ps;
    m_i = m_new;
    f16x4 pf;
#pragma unroll
    for (int r = 0; r < 4; r++) pf[r] = (_Float16)p[r];
#pragma unroll
    for (int t = 0; t < 8; t++) {
      acc_o[t] *= alpha;
      acc_o[t] = __builtin_amdgcn_mfma_f32_16x16x16f16(vf[t], pf, acc_o[t], 0, 0, 0);
    }
  }

  // epilogue: O^T[d][q] -> LDS as O[q][d] (stride 132), coalesced bf16 store
  __syncthreads();
  const float inv_l = 1.0f / l_i;
#pragma unroll
  for (int t = 0; t < 8; t++)
#pragma unroll
    for (int r = 0; r < 4; r++)
      smem_f[(w*16 + qc)*132 + t*16 + g*4 + r] = acc_o[t][r] * inv_l;
  __syncthreads();

  const int row = threadIdx.x >> 2;          // 0..63
  const int c0  = (threadIdx.x & 3) * 32;
  unsigned short* Os = (unsigned short*)O;
  const size_t obase = ((size_t)b*S_ + x*64 + row)*E_ + h*D_;
#pragma unroll
  for (int i = 0; i < 8; i++) {
    const f32x4 v4 = *(const f32x4*)(smem_f + row*132 + c0 + i*4);
    u16x4 o4;
    o4.x = f2bf(v4.x); o4.y = f2bf(v4.y); o4.z = f2bf(v4.z); o4.w = f2bf(v4.w);
    *(u16x4*)(Os + obase + c0 + i*4) = o4;
  }
#undef ISSUE_LOAD
#undef COMPUTE
}

extern "C" void kernel_launch(void* const* d_in, const int* in_sizes, int n_in,
                              void* d_out, int out_size, void* d_ws, size_t ws_size,
                              hipStream_t stream)
{
  (void)in_sizes; (void)n_in; (void)out_size; (void)ws_size;
  const float* act = (const float*)d_in[0];
  const float* Wq  = (const float*)d_in[1];
  const float* Wk  = (const float*)d_in[2];
  const float* Wv  = (const float*)d_in[3];
  const float* Wo  = (const float*)d_in[4];

  __hip_bfloat16* actb = (__hip_bfloat16*)d_ws;
  __hip_bfloat16* Wqb  = actb + ELEMS;
  __hip_bfloat16* Wkb  = Wqb + WELEMS;
  __hip_bfloat16* Wvb  = Wkb + WELEMS;
  __hip_bfloat16* Wob  = Wvb + WELEMS;
  __hip_bfloat16* Q    = Wob + WELEMS;
  __hip_bfloat16* Kp   = Q + ELEMS;
  __hip_bfloat16* V    = Kp + ELEMS;
  _Float16*       VT   = (_Float16*)(V + ELEMS);
  __hip_bfloat16* AO   = V;   // V dead after transpose_v; reuse for attn output

  cvt_f32_bf16<<<ELEMS/4/256, 256, 0, stream>>>(act, (unsigned short*)actb, ELEMS/4);
  cvt4_f32_bf16<<<dim3(WELEMS/4/256, 4), 256, 0, stream>>>(
      Wq, Wk, Wv, Wo,
      (unsigned short*)Wqb, (unsigned short*)Wkb,
      (unsigned short*)Wvb, (unsigned short*)Wob, WELEMS/4);

  // Fused QKV projection: Wqb/Wkb/Wvb are contiguous => one [4096 x 6144 x 2048]
  // GEMM; Q/Kp/V outputs contiguous (ELEMS apart), OUTMODE 3 routes by col>>11.
  const dim3 gq(3*E_/128, (B_*S_)/128);
  gemm_bt<3><<<gq, 256, 0, stream>>>(actb, Wqb, Q, B_*S_, 3*E_, E_);

  xpos_rotary<<<(B_*S_*H_*64)/256, 256, 0, stream>>>(Q, Kp);
  transpose_v<<<dim3(S_/32, D_/32, B_*H_), dim3(32, 8), 0, stream>>>(V, VT);
  attn_fwd<<<1024, 256, 0, stream>>>(Q, Kp, VT, AO);

  const dim3 gg(E_/128, (B_*S_)/128);
  gemm_bt<1><<<gg, 256, 0, stream>>>(AO, Wob, d_out, B_*S_, E_, E_);
}

// Round 2
// 437.533 us; speedup vs baseline: 1.3375x; 1.3375x over previous
//
#include <hip/hip_runtime.h>
#include <hip/hip_bf16.h>

typedef __attribute__((ext_vector_type(8))) short bf16x8;
typedef __attribute__((ext_vector_type(4))) float f32x4;
typedef __attribute__((ext_vector_type(4))) _Float16 f16x4;
typedef __attribute__((ext_vector_type(8))) _Float16 f16x8;
typedef __attribute__((ext_vector_type(4))) unsigned short u16x4;

#define B_ 2
#define S_ 2048
#define E_ 2048
#define H_ 16
#define D_ 128
#define ELEMS (B_*S_*E_)   // 8388608 elements of [B,S,2048]
#define WELEMS (E_*E_)     // 4194304 elements per weight matrix

__device__ __forceinline__ unsigned short f2bf(float x) {
  unsigned int u = __float_as_uint(x);
  u += 0x7fffu + ((u >> 16) & 1u);
  return (unsigned short)(u >> 16);
}

__device__ __forceinline__ void async_load16(const void* g, void* l) {
  __builtin_amdgcn_global_load_lds(
      (const __attribute__((address_space(1))) unsigned int*)g,
      (__attribute__((address_space(3))) unsigned int*)l, 16, 0, 0);
}

// f32 -> bf16 (RNE), vectorized x4. n4 = n/4.
__global__ __launch_bounds__(256)
void cvt_f32_bf16(const float* __restrict__ src, unsigned short* __restrict__ dst, int n4)
{
  const int i = blockIdx.x * 256 + threadIdx.x;
  if (i < n4) {
    const f32x4 v = ((const f32x4*)src)[i];
    u16x4 o;
    o.x = f2bf(v.x); o.y = f2bf(v.y); o.z = f2bf(v.z); o.w = f2bf(v.w);
    ((u16x4*)dst)[i] = o;
  }
}

// four equally-sized weight tensors in one launch (blockIdx.y selects)
__global__ __launch_bounds__(256)
void cvt4_f32_bf16(const float* __restrict__ s0, const float* __restrict__ s1,
                   const float* __restrict__ s2, const float* __restrict__ s3,
                   unsigned short* __restrict__ d0, unsigned short* __restrict__ d1,
                   unsigned short* __restrict__ d2, unsigned short* __restrict__ d3,
                   int n4)
{
  const int i = blockIdx.x * 256 + threadIdx.x;
  if (i >= n4) return;
  const float* s; unsigned short* d;
  switch (blockIdx.y) {
    case 0: s = s0; d = d0; break;
    case 1: s = s1; d = d1; break;
    case 2: s = s2; d = d2; break;
    default: s = s3; d = d3; break;
  }
  const f32x4 v = ((const f32x4*)s)[i];
  u16x4 o;
  o.x = f2bf(v.x); o.y = f2bf(v.y); o.z = f2bf(v.z); o.w = f2bf(v.w);
  ((u16x4*)d)[i] = o;
}

// C[m][n] = sum_k A[m][k] * Bw[n][k]   (torch Linear / B^T layout), bf16 in,
// f32 accumulate. OUTMODE: 0 = bf16 row-major, 1 = f32 row-major,
// 2 = bf16 head-major [b, h, s, d] (row=b*2048+s, col=h*128+d),
// 3 = fused-QKV head-major: col in [0, 3*2048); tensor = col>>11 selects
//     Q/K/V (contiguous, ELEMS apart), then head-major like mode 2.
template<int OUTMODE>
__global__ __launch_bounds__(256)
void gemm_bt(const __hip_bfloat16* __restrict__ A,
             const __hip_bfloat16* __restrict__ Bw,
             void* __restrict__ C, int M, int N, int K)
{
  __shared__ __hip_bfloat16 As[128*32];
  __shared__ __hip_bfloat16 Bs[128*32];
  const int tid  = threadIdx.x;
  const int lane = tid & 63;
  const int w    = tid >> 6;
  const int m0 = blockIdx.y * 128;
  const int n0 = blockIdx.x * 128;
  const int wm = (w >> 1) * 64;
  const int wn = (w & 1) * 64;
  const int lrow = lane >> 2;
  const int lcol = (lane & 3) * 8;
  const int fr = lane & 15;
  const int fg = lane >> 4;

  f32x4 acc[4][4];
#pragma unroll
  for (int i = 0; i < 4; i++)
#pragma unroll
    for (int j = 0; j < 4; j++) acc[i][j] = (f32x4)0.0f;

  for (int k0 = 0; k0 < K; k0 += 32) {
    __syncthreads();
#pragma unroll
    for (int s = 0; s < 2; s++) {
      const int rbase = s*64 + w*16;
      async_load16(A  + (size_t)(m0 + rbase + lrow)*K + k0 + lcol, As + rbase*32);
      async_load16(Bw + (size_t)(n0 + rbase + lrow)*K + k0 + lcol, Bs + rbase*32);
    }
    __syncthreads();
    bf16x8 af[4], bfr[4];
#pragma unroll
    for (int i = 0; i < 4; i++) {
      af[i]  = *(const bf16x8*)(As + (wm + i*16 + fr)*32 + fg*8);
      bfr[i] = *(const bf16x8*)(Bs + (wn + i*16 + fr)*32 + fg*8);
    }
#pragma unroll
    for (int i = 0; i < 4; i++)
#pragma unroll
      for (int j = 0; j < 4; j++)
        acc[i][j] = __builtin_amdgcn_mfma_f32_16x16x32_bf16(af[i], bfr[j], acc[i][j], 0, 0, 0);
  }

#pragma unroll
  for (int i = 0; i < 4; i++) {
    const int row = m0 + wm + i*16 + fg*4;
#pragma unroll
    for (int j = 0; j < 4; j++) {
      const int col = n0 + wn + j*16 + fr;
#pragma unroll
      for (int r = 0; r < 4; r++) {
        if (OUTMODE == 1) {
          ((float*)C)[(size_t)(row + r)*N + col] = acc[i][j][r];
        } else if (OUTMODE == 0) {
          ((unsigned short*)C)[(size_t)(row + r)*N + col] = f2bf(acc[i][j][r]);
        } else if (OUTMODE == 2) {
          const int rr = row + r;
          const int b = rr >> 11, s = rr & 2047;
          const int h = col >> 7, d = col & 127;
          ((unsigned short*)C)[(((size_t)(b*H_ + h) << 11) + s)*D_ + d] = f2bf(acc[i][j][r]);
        } else {   // OUTMODE == 3: fused QKV, outputs contiguous ELEMS apart
          const int rr = row + r;
          const int b = rr >> 11, s = rr & 2047;
          const int t = col >> 11;             // 0=Q 1=K 2=V
          const int h = (col >> 7) & 15, d = col & 127;
          ((unsigned short*)C)[(size_t)t*ELEMS +
              (((size_t)(b*H_ + h) << 11) + s)*D_ + d] = f2bf(acc[i][j][r]);
        }
      }
    }
  }
}

// xpos rotary, in place on head-major bf16 Q and K [b,h,s,d].
__global__ __launch_bounds__(256)
void xpos_rotary(__hip_bfloat16* __restrict__ Q, __hip_bfloat16* __restrict__ Kt)
{
  const int idx = blockIdx.x * 256 + threadIdx.x;   // [0, B*H*S*64)
  const int j = idx & 63;
  const int s = (idx >> 6) & 2047;
  const float seq = (float)(s - 1024) * (1.0f/512.0f);
  const float dr = 2.0f + 2.0f*(float)j;
  const float theta = expf(dr * (1.0f/128.0f) * -9.210340371976184f);
  const float zeta  = (dr * (1.0f/64.0f) + 51.2f) * (1.0f/52.2f);
  const float ang = seq * theta;
  const float c  = cosf(ang);
  const float sn = sinf(ang);
  const float t  = expf(seq * logf(zeta));
  const float it = 1.0f / t;

  const size_t base = (size_t)(idx >> 6) * 128 + 2*j;
  unsigned short* Qs = (unsigned short*)Q;
  unsigned short* Ks = (unsigned short*)Kt;
  const float q0 = __bfloat162float(Q[base]),  q1 = __bfloat162float(Q[base+1]);
  Qs[base]   = f2bf((q0*c - q1*sn) * t);
  Qs[base+1] = f2bf((q1*c + q0*sn) * t);
  const float k0 = __bfloat162float(Kt[base]), k1 = __bfloat162float(Kt[base+1]);
  Ks[base]   = f2bf((k0*c - k1*sn) * it);
  Ks[base+1] = f2bf((k1*c + k0*sn) * it);
}

// Vh [b,h,s,d] bf16 -> VT3 packed f16:
// per (bh, kt=s/64) 16-KB tile, inner offset = d*64 + g*16 + half*8 + s1*4 + r
// where key=s%64 = (half*2+s1)*16 + g*4 + r.
__global__ __launch_bounds__(256)
void transpose_v(const __hip_bfloat16* __restrict__ Vh, _Float16* __restrict__ VT3)
{
  __shared__ float tile[32][33];
  const int tx = threadIdx.x, ty = threadIdx.y;      // block (32, 8)
  const int bh = blockIdx.z;
  const int s0 = blockIdx.x * 32, d0 = blockIdx.y * 32;
  const int kt = s0 >> 6, koff = s0 & 63;
#pragma unroll
  for (int r = 0; r < 4; r++) {
    const int s = s0 + ty + r*8;
    tile[ty + r*8][tx] = __bfloat162float(Vh[((size_t)bh*S_ + s)*D_ + d0 + tx]);
  }
  __syncthreads();
  const int key = koff + tx;
  const int g = (key >> 2) & 3, rr = key & 3, half = (key >> 5) & 1, s1 = (key >> 4) & 1;
  const size_t base = (size_t)bh*S_*D_ + (size_t)kt*8192 + g*16 + half*8 + s1*4 + rr;
#pragma unroll
  for (int r = 0; r < 4; r++) {
    const int d = d0 + ty + r*8;
    VT3[base + d*64] = (_Float16)tile[tx][ty + r*8];
  }
}

// Flash attention, causal. R1 rewrite: K/V staged in LDS once per block via
// async global_load_lds (DMA is immune to regalloc - the R0 register ping-pong
// was serialized by the compiler at VGPR=112, exposing full load latency every
// iteration: MfmaUtil 8%). 32-key tiles, double-buffered; all 4 waves share
// the staged tile and iterate the same 2x+2 tiles (causal mask absorbs the
// diagonal waste; key 0 is always valid so m_i leaves -1e30 on tile 0).
// Swizzles (both-sides rule): K read byte ^= (key&7)<<4, V slot g ^= (d>>1)&3;
// inverse applied on the per-lane global source address of the DMA.
// LDS = 2*(8K+8K) staged, union'd with 33.8KB epilogue -> 4 blocks/CU kept.
__global__ __launch_bounds__(256, 2)
void attn_fwd(const __hip_bfloat16* __restrict__ Qh,
              const __hip_bfloat16* __restrict__ Kh,
              const _Float16* __restrict__ VT3,
              __hip_bfloat16* __restrict__ O)
{
  __shared__ union {
    struct { unsigned short Kt[2][4096]; _Float16 Vt[2][4096]; } st;
    float ep[64*132];
  } sh;

  const int lane = threadIdx.x & 63;
  const int w    = threadIdx.x >> 6;
  const int L  = blockIdx.x;                   // 0..1023
  const int bh = (L & 7) + 8*((L >> 3) & 3);   // bh pinned to XCD = bh&7
  const int x  = 31 - (L >> 5);                // longest-first
  const int b = bh >> 4, h = bh & 15;
  const int q0 = x*64 + w*16;
  const int qc = lane & 15;
  const int g  = lane >> 4;
  const int qv = q0 + qc;

  const __hip_bfloat16* Kb = Kh + (size_t)bh*S_*D_;
  const _Float16* vtb = VT3 + (size_t)bh*S_*D_;

  const int kswz  = (qc & 7) << 4;                     // K read swizzle (bytes)
  const int vbase = qc*64 + ((g ^ ((qc >> 1) & 3)) << 4);  // V read base (bytes)

// stage 32-key tile P into buffer BUF: K 8KB (8 chunks) + V 8KB (8 chunks),
// wave w issues chunks 2w, 2w+1 of each. DMA dest is linear (base + lane*16);
// the read-side swizzle is pre-applied (inverted) on the global source addr.
#define STAGE(BUF, P) do {                                                       \
    const int kb0_ = (P)*32;                                                     \
    _Pragma("unroll")                                                            \
    for (int ii = 0; ii < 2; ii++) {                                             \
      const int chunk = w*2 + ii;                                                \
      const int key   = chunk*4 + (lane >> 4);                                   \
      const int srcin = ((lane & 15)*16) ^ ((key & 7) << 4);                     \
      async_load16((const char*)Kb + (size_t)(kb0_ + key)*256 + srcin,           \
                   (char*)sh.st.Kt[BUF] + chunk*1024);                           \
    }                                                                            \
    const int kt_ = (P) >> 1, h_ = (P) & 1;                                      \
    _Pragma("unroll")                                                            \
    for (int ii = 0; ii < 2; ii++) {                                             \
      const int chunk = w*2 + ii;                                                \
      const int dd = chunk*16 + (lane >> 2);                                     \
      const int gg = (lane & 3) ^ ((lane >> 3) & 3);                             \
      async_load16((const char*)vtb + ((size_t)kt_*8192 + dd*64 + gg*16 + h_*8)*2,\
                   (char*)sh.st.Vt[BUF] + chunk*1024);                           \
    }                                                                            \
  } while (0)

#define COMPUTE(BUF, P) do {                                                     \
    const int k0_ = (P)*32;                                                      \
    const char* Kl = (const char*)sh.st.Kt[BUF];                                 \
    const char* Vl = (const char*)sh.st.Vt[BUF];                                 \
    bf16x8 ka[4], kbb[4]; f16x8 vv[8];                                           \
    _Pragma("unroll")                                                            \
    for (int c = 0; c < 4; c++) {                                                \
      const int off = (c*64 + g*16) ^ kswz;                                      \
      ka[c]  = *(const bf16x8*)(Kl + qc*256 + off);                              \
      kbb[c] = *(const bf16x8*)(Kl + (16 + qc)*256 + off);                       \
    }                                                                            \
    _Pragma("unroll")                                                            \
    for (int t = 0; t < 8; t++) vv[t] = *(const f16x8*)(Vl + t*1024 + vbase);    \
    f32x4 sA = (f32x4)0.0f, sB = (f32x4)0.0f;                                    \
    _Pragma("unroll")                                                            \
    for (int c = 0; c < 4; c++) {                                                \
      sA = __builtin_amdgcn_mfma_f32_16x16x32_bf16(ka[c],  qf[c], sA, 0, 0, 0);  \
      sB = __builtin_amdgcn_mfma_f32_16x16x32_bf16(kbb[c], qf[c], sB, 0, 0, 0);  \
    }                                                                            \
    float sv[8];                                                                 \
    _Pragma("unroll")                                                            \
    for (int r = 0; r < 4; r++) {                                                \
      sv[r]   = (k0_      + g*4 + r <= qv) ? sA[r]*scale : -1e30f;               \
      sv[4+r] = (k0_ + 16 + g*4 + r <= qv) ? sB[r]*scale : -1e30f;               \
    }                                                                            \
    float mx = sv[0];                                                            \
    _Pragma("unroll")                                                            \
    for (int j = 1; j < 8; j++) mx = fmaxf(mx, sv[j]);                           \
    mx = fmaxf(mx, __shfl_xor(mx, 16));                                          \
    mx = fmaxf(mx, __shfl_xor(mx, 32));                                          \
    const float m_new = fmaxf(m_i, mx);                                          \
    const float alpha = __expf(m_i - m_new);                                     \
    float p[8], ps = 0.0f;                                                       \
    _Pragma("unroll")                                                            \
    for (int j = 0; j < 8; j++) { p[j] = __expf(sv[j] - m_new); ps += p[j]; }    \
    ps += __shfl_xor(ps, 16);                                                    \
    ps += __shfl_xor(ps, 32);                                                    \
    l_i = l_i*alpha + ps;                                                        \
    m_i = m_new;                                                                 \
    f16x4 pA, pB;                                                                \
    _Pragma("unroll")                                                            \
    for (int r = 0; r < 4; r++) { pA[r] = (_Float16)p[r]; pB[r] = (_Float16)p[4+r]; } \
    _Pragma("unroll")                                                            \
    for (int t = 0; t < 8; t++) acc_o[t] *= alpha;                               \
    _Pragma("unroll")                                                            \
    for (int t = 0; t < 8; t++) {                                                \
      const f16x4 vA = __builtin_shufflevector(vv[t], vv[t], 0, 1, 2, 3);        \
      const f16x4 vB = __builtin_shufflevector(vv[t], vv[t], 4, 5, 6, 7);        \
      acc_o[t] = __builtin_amdgcn_mfma_f32_16x16x16f16(vA, pA, acc_o[t], 0, 0, 0); \
      acc_o[t] = __builtin_amdgcn_mfma_f32_16x16x16f16(vB, pB, acc_o[t], 0, 0, 0); \
    }                                                                            \
  } while (0)

  // issue tile-0 DMA first so it flies under the Q register loads
  STAGE(0, 0);

  bf16x8 qf[4];
  {
    const __hip_bfloat16* qrow = Qh + ((size_t)bh*S_ + qv)*D_ + g*8;
#pragma unroll
    for (int c = 0; c < 4; c++) qf[c] = *(const bf16x8*)(qrow + c*32);
  }

  f32x4 acc_o[8];
#pragma unroll
  for (int t = 0; t < 8; t++) acc_o[t] = (f32x4)0.0f;
  float m_i = -1e30f, l_i = 0.0f;
  const float scale = 0.08838834764831845f;   // 1/sqrt(128)

  const int ntile = 2*x + 2;       // 32-key tiles, uniform across the block

  __syncthreads();                 // drains vmcnt(0): tile 0 resident

  for (int p = 0; p < ntile; ++p) {
    if (p + 1 < ntile) STAGE((p + 1) & 1, p + 1);   // async prefetch
    COMPUTE(p & 1, p);
    __syncthreads();               // drain: tile p+1 resident, buf p free
  }

  // epilogue: O^T[d][q] -> LDS as O[q][d] (stride 132), coalesced bf16 store.
  // Last loop __syncthreads guarantees stage buffers are dead; ep aliases them.
  const float inv_l = 1.0f / l_i;
#pragma unroll
  for (int t = 0; t < 8; t++)
#pragma unroll
    for (int r = 0; r < 4; r++)
      sh.ep[(w*16 + qc)*132 + t*16 + g*4 + r] = acc_o[t][r] * inv_l;
  __syncthreads();

  const int row = threadIdx.x >> 2;          // 0..63
  const int c0  = (threadIdx.x & 3) * 32;
  unsigned short* Os = (unsigned short*)O;
  const size_t obase = ((size_t)b*S_ + x*64 + row)*E_ + h*D_;
#pragma unroll
  for (int i = 0; i < 8; i++) {
    const f32x4 v4 = *(const f32x4*)(sh.ep + row*132 + c0 + i*4);
    u16x4 o4;
    o4.x = f2bf(v4.x); o4.y = f2bf(v4.y); o4.z = f2bf(v4.z); o4.w = f2bf(v4.w);
    *(u16x4*)(Os + obase + c0 + i*4) = o4;
  }
#undef STAGE
#undef COMPUTE
}

extern "C" void kernel_launch(void* const* d_in, const int* in_sizes, int n_in,
                              void* d_out, int out_size, void* d_ws, size_t ws_size,
                              hipStream_t stream)
{
  (void)in_sizes; (void)n_in; (void)out_size; (void)ws_size;
  const float* act = (const float*)d_in[0];
  const float* Wq  = (const float*)d_in[1];
  const float* Wk  = (const float*)d_in[2];
  const float* Wv  = (const float*)d_in[3];
  const float* Wo  = (const float*)d_in[4];

  __hip_bfloat16* actb = (__hip_bfloat16*)d_ws;
  __hip_bfloat16* Wqb  = actb + ELEMS;
  __hip_bfloat16* Wkb  = Wqb + WELEMS;
  __hip_bfloat16* Wvb  = Wkb + WELEMS;
  __hip_bfloat16* Wob  = Wvb + WELEMS;
  __hip_bfloat16* Q    = Wob + WELEMS;
  __hip_bfloat16* Kp   = Q + ELEMS;
  __hip_bfloat16* V    = Kp + ELEMS;
  _Float16*       VT   = (_Float16*)(V + ELEMS);
  __hip_bfloat16* AO   = V;   // V dead after transpose_v; reuse for attn output

  cvt_f32_bf16<<<ELEMS/4/256, 256, 0, stream>>>(act, (unsigned short*)actb, ELEMS/4);
  cvt4_f32_bf16<<<dim3(WELEMS/4/256, 4), 256, 0, stream>>>(
      Wq, Wk, Wv, Wo,
      (unsigned short*)Wqb, (unsigned short*)Wkb,
      (unsigned short*)Wvb, (unsigned short*)Wob, WELEMS/4);

  // Fused QKV projection: Wqb/Wkb/Wvb are contiguous => one [4096 x 6144 x 2048]
  // GEMM; Q/Kp/V outputs contiguous (ELEMS apart), OUTMODE 3 routes by col>>11.
  const dim3 gq(3*E_/128, (B_*S_)/128);
  gemm_bt<3><<<gq, 256, 0, stream>>>(actb, Wqb, Q, B_*S_, 3*E_, E_);

  xpos_rotary<<<(B_*S_*H_*64)/256, 256, 0, stream>>>(Q, Kp);
  transpose_v<<<dim3(S_/32, D_/32, B_*H_), dim3(32, 8), 0, stream>>>(V, VT);
  attn_fwd<<<1024, 256, 0, stream>>>(Q, Kp, VT, AO);

  const dim3 gg(E_/128, (B_*S_)/128);
  gemm_bt<1><<<gg, 256, 0, stream>>>(AO, Wob, d_out, B_*S_, E_, E_);
}

// Round 3
// 411.361 us; speedup vs baseline: 1.4226x; 1.0636x over previous
//
#include <hip/hip_runtime.h>
#include <hip/hip_bf16.h>

typedef __attribute__((ext_vector_type(8))) short bf16x8;
typedef __attribute__((ext_vector_type(4))) float f32x4;
typedef __attribute__((ext_vector_type(4))) _Float16 f16x4;
typedef __attribute__((ext_vector_type(8))) _Float16 f16x8;
typedef __attribute__((ext_vector_type(4))) unsigned short u16x4;

#define B_ 2
#define S_ 2048
#define E_ 2048
#define H_ 16
#define D_ 128
#define ELEMS (B_*S_*E_)   // 8388608 elements of [B,S,2048]
#define WELEMS (E_*E_)     // 4194304 elements per weight matrix

__device__ __forceinline__ unsigned short f2bf(float x) {
  unsigned int u = __float_as_uint(x);
  u += 0x7fffu + ((u >> 16) & 1u);
  return (unsigned short)(u >> 16);
}

__device__ __forceinline__ void async_load16(const void* g, void* l) {
  __builtin_amdgcn_global_load_lds(
      (const __attribute__((address_space(1))) unsigned int*)g,
      (__attribute__((address_space(3))) unsigned int*)l, 16, 0, 0);
}

// f32 -> bf16 (RNE), vectorized x4. n4 = n/4.
__global__ __launch_bounds__(256)
void cvt_f32_bf16(const float* __restrict__ src, unsigned short* __restrict__ dst, int n4)
{
  const int i = blockIdx.x * 256 + threadIdx.x;
  if (i < n4) {
    const f32x4 v = ((const f32x4*)src)[i];
    u16x4 o;
    o.x = f2bf(v.x); o.y = f2bf(v.y); o.z = f2bf(v.z); o.w = f2bf(v.w);
    ((u16x4*)dst)[i] = o;
  }
}

// four equally-sized weight tensors in one launch (blockIdx.y selects)
__global__ __launch_bounds__(256)
void cvt4_f32_bf16(const float* __restrict__ s0, const float* __restrict__ s1,
                   const float* __restrict__ s2, const float* __restrict__ s3,
                   unsigned short* __restrict__ d0, unsigned short* __restrict__ d1,
                   unsigned short* __restrict__ d2, unsigned short* __restrict__ d3,
                   int n4)
{
  const int i = blockIdx.x * 256 + threadIdx.x;
  if (i >= n4) return;
  const float* s; unsigned short* d;
  switch (blockIdx.y) {
    case 0: s = s0; d = d0; break;
    case 1: s = s1; d = d1; break;
    case 2: s = s2; d = d2; break;
    default: s = s3; d = d3; break;
  }
  const f32x4 v = ((const f32x4*)s)[i];
  u16x4 o;
  o.x = f2bf(v.x); o.y = f2bf(v.y); o.z = f2bf(v.z); o.w = f2bf(v.w);
  ((u16x4*)d)[i] = o;
}

// ---------------------------------------------------------------------------
// Legacy 128x128 GEMM (m97 structure) - retained for the Wo projection where
// the 256^2 kernel would only fill 128 of 256 CUs.
// C[m][n] = sum_k A[m][k] * Bw[n][k]. OUTMODE as documented below.
template<int OUTMODE>
__global__ __launch_bounds__(256)
void gemm_bt(const __hip_bfloat16* __restrict__ A,
             const __hip_bfloat16* __restrict__ Bw,
             void* __restrict__ C, int M, int N, int K)
{
  __shared__ __hip_bfloat16 As[128*32];
  __shared__ __hip_bfloat16 Bs[128*32];
  const int tid  = threadIdx.x;
  const int lane = tid & 63;
  const int w    = tid >> 6;
  const int m0 = blockIdx.y * 128;
  const int n0 = blockIdx.x * 128;
  const int wm = (w >> 1) * 64;
  const int wn = (w & 1) * 64;
  const int lrow = lane >> 2;
  const int lcol = (lane & 3) * 8;
  const int fr = lane & 15;
  const int fg = lane >> 4;

  f32x4 acc[4][4];
#pragma unroll
  for (int i = 0; i < 4; i++)
#pragma unroll
    for (int j = 0; j < 4; j++) acc[i][j] = (f32x4)0.0f;

  for (int k0 = 0; k0 < K; k0 += 32) {
    __syncthreads();
#pragma unroll
    for (int s = 0; s < 2; s++) {
      const int rbase = s*64 + w*16;
      async_load16(A  + (size_t)(m0 + rbase + lrow)*K + k0 + lcol, As + rbase*32);
      async_load16(Bw + (size_t)(n0 + rbase + lrow)*K + k0 + lcol, Bs + rbase*32);
    }
    __syncthreads();
    bf16x8 af[4], bfr[4];
#pragma unroll
    for (int i = 0; i < 4; i++) {
      af[i]  = *(const bf16x8*)(As + (wm + i*16 + fr)*32 + fg*8);
      bfr[i] = *(const bf16x8*)(Bs + (wn + i*16 + fr)*32 + fg*8);
    }
#pragma unroll
    for (int i = 0; i < 4; i++)
#pragma unroll
      for (int j = 0; j < 4; j++)
        acc[i][j] = __builtin_amdgcn_mfma_f32_16x16x32_bf16(af[i], bfr[j], acc[i][j], 0, 0, 0);
  }

#pragma unroll
  for (int i = 0; i < 4; i++) {
    const int row = m0 + wm + i*16 + fg*4;
#pragma unroll
    for (int j = 0; j < 4; j++) {
      const int col = n0 + wn + j*16 + fr;
#pragma unroll
      for (int r = 0; r < 4; r++) {
        if (OUTMODE == 1) {
          ((float*)C)[(size_t)(row + r)*N + col] = acc[i][j][r];
        } else if (OUTMODE == 0) {
          ((unsigned short*)C)[(size_t)(row + r)*N + col] = f2bf(acc[i][j][r]);
        } else if (OUTMODE == 2) {
          const int rr = row + r;
          const int b = rr >> 11, s = rr & 2047;
          const int h = col >> 7, d = col & 127;
          ((unsigned short*)C)[(((size_t)(b*H_ + h) << 11) + s)*D_ + d] = f2bf(acc[i][j][r]);
        } else {
          const int rr = row + r;
          const int b = rr >> 11, s = rr & 2047;
          const int t = col >> 11;
          const int h = (col >> 7) & 15, d = col & 127;
          ((unsigned short*)C)[(size_t)t*ELEMS +
              (((size_t)(b*H_ + h) << 11) + s)*D_ + d] = f2bf(acc[i][j][r]);
        }
      }
    }
  }
}

// ---------------------------------------------------------------------------
// 256x256-tile 8-phase GEMM (HK-style schedule, plain HIP). 512 threads =
// 8 waves (2M x 4N), per-wave output 128x64, BK=64 split into two k-halves.
// LDS ring: 2 buffers x {A[2][256][32], B[2][256][32]} bf16 = 128 KiB.
// Swizzle: 16B-slot ^= (row&3); DMA dest linear, inverse swizzle applied on
// the per-lane global source (both-sides rule). Per phase: {ds_read 4-8 x
// b128 | stage 2 x global_load_lds | s_barrier | lgkmcnt(0) | setprio(1)
// 16 MFMA setprio(0)}; counted vmcnt(4) twice per K-tile (never 0 in loop);
// raw s_barrier only (no __syncthreads -> no vmcnt drain at barriers).
template<int OUTMODE>
__global__ __launch_bounds__(512, 2)
void gemm_bt8(const __hip_bfloat16* __restrict__ A,
              const __hip_bfloat16* __restrict__ Bw,
              void* __restrict__ C, int M, int N, int K)
{
  extern __shared__ char lds[];
  const int tid  = threadIdx.x;
  const int lane = tid & 63;
  const int w    = tid >> 6;        // 0..7
  const int fr   = lane & 15;
  const int fg   = lane >> 4;       // 0..3

  // XCD-aware swizzle of the linear block id (grid % 8 == 0)
  const int nblk = N >> 8;
  const int cpx  = gridDim.x >> 3;
  const int lin  = blockIdx.x;
  const int swz  = (lin & 7) * cpx + (lin >> 3);
  const int m0 = (swz / nblk) << 8;
  const int n0 = (swz % nblk) << 8;

  // LDS read geometry: addr = buf*65536 + (B?32768:0) + kk*16384
  //                         + row*64 + ((slot ^ (row&3))<<4); row&3 == fr&3.
  const int Ssw = (fg ^ (fr & 3)) << 4;
  const int pA  = ((w >> 2) * 128 + fr) * 64 + Ssw;   // + mi*1024
  const int pB  = 32768 + ((w & 3) * 64 + fr) * 64 + Ssw;

  // Staging geometry: per stage-unit (one operand, one k-half: 256 rows x 32k
  // = 16 KB) each thread issues 2 DMAs. chunk c = (w*2+ii)*64 + lane;
  // row = c>>2, dest slot = c&3, source k-group = (c&3)^(row&3).
  const int r0 = w * 32 + (lane >> 2);                 // row for ii=0; ii=1: +16
  const int ks = ((lane & 3) ^ ((lane >> 2) & 3)) * 8; // source k offset (elems)
  const __hip_bfloat16* Asrc = A  + (size_t)(m0 + r0) * K + ks;
  const __hip_bfloat16* Bsrc = Bw + (size_t)(n0 + r0) * K + ks;
  const int dgrp = w * 2048;                           // (w*2)*1024 dest base

#define STG(NB, OPB, KH, KT) do {                                              \
    const size_t ko_ = (size_t)(KT)*64 + (KH)*32;                              \
    const __hip_bfloat16* sp_ = (OPB) ? Bsrc : Asrc;                           \
    char* dp_ = lds + (NB)*65536 + (OPB)*32768 + (KH)*16384 + dgrp;            \
    async_load16(sp_ + ko_, dp_);                                              \
    async_load16(sp_ + (size_t)16*K + ko_, dp_ + 1024);                        \
  } while (0)

#define RDA(DST, KK, BB, MI0) do {                                             \
    const char* p_ = lds + (BB)*65536 + (KK)*16384 + pA + (MI0)*1024;          \
    DST[0] = *(const bf16x8*)(p_);                                             \
    DST[1] = *(const bf16x8*)(p_ + 1024);                                      \
    DST[2] = *(const bf16x8*)(p_ + 2048);                                      \
    DST[3] = *(const bf16x8*)(p_ + 3072);                                      \
  } while (0)

#define RDB(DST, KK, BB) do {                                                  \
    const char* p_ = lds + (BB)*65536 + (KK)*16384 + pB;                       \
    DST[0] = *(const bf16x8*)(p_);                                             \
    DST[1] = *(const bf16x8*)(p_ + 1024);                                      \
    DST[2] = *(const bf16x8*)(p_ + 2048);                                      \
    DST[3] = *(const bf16x8*)(p_ + 3072);                                      \
  } while (0)

#define MFMA16(MI0, AR, BR)                                                    \
    _Pragma("unroll")                                                          \
    for (int i_ = 0; i_ < 4; i_++)                                             \
    _Pragma("unroll")                                                          \
    for (int j_ = 0; j_ < 4; j_++)                                             \
      acc[(MI0)+i_][j_] = __builtin_amdgcn_mfma_f32_16x16x32_bf16(             \
          AR[i_], BR[j_], acc[(MI0)+i_][j_], 0, 0, 0)

#define BARX() __builtin_amdgcn_s_barrier()
#define LGKM0() do { asm volatile("s_waitcnt lgkmcnt(0)" ::: "memory");        \
                     __builtin_amdgcn_sched_barrier(0); } while (0)
#define VMW(NN) asm volatile("s_waitcnt vmcnt(" #NN ")" ::: "memory")
#define PRIO(P) __builtin_amdgcn_s_setprio(P)

  f32x4 acc[8][4];
#pragma unroll
  for (int i = 0; i < 8; i++)
#pragma unroll
    for (int j = 0; j < 4; j++) acc[i][j] = (f32x4)0.0f;

  // prologue: stage tile 0 (units Ak0, Bk0, Ak1, Bk1) into buffer 0
  STG(0, 0, 0, 0);
  STG(0, 1, 0, 0);
  STG(0, 0, 1, 0);
  STG(0, 1, 1, 0);
  VMW(4);          // Ak0+Bk0 of tile 0 resident (Ak1/Bk1 still in flight)
  BARX();

  const int nk = K >> 6;   // K-tiles of 64
  bf16x8 aR[4], bR[4];

  for (int t = 0; t < nk - 1; ++t) {
    const int bb = t & 1, nb = bb ^ 1;
    // P0: kk=0, M-quads 0-1
    RDA(aR, 0, bb, 0); RDB(bR, 0, bb);
    STG(nb, 0, 0, t + 1);
    BARX(); LGKM0();
    PRIO(1); MFMA16(0, aR, bR); PRIO(0);
    BARX();
    // P1: kk=0, M-quads 2-3
    RDA(aR, 0, bb, 4);
    STG(nb, 1, 0, t + 1);
    BARX(); LGKM0();
    PRIO(1); MFMA16(4, aR, bR); PRIO(0);
    VMW(4);        // gate: Ak1+Bk1 of tile t resident
    BARX();
    // P2: kk=1, M-quads 0-1
    RDA(aR, 1, bb, 0); RDB(bR, 1, bb);
    STG(nb, 0, 1, t + 1);
    BARX(); LGKM0();
    PRIO(1); MFMA16(0, aR, bR); PRIO(0);
    BARX();
    // P3: kk=1, M-quads 2-3
    RDA(aR, 1, bb, 4);
    STG(nb, 1, 1, t + 1);
    BARX(); LGKM0();
    PRIO(1); MFMA16(4, aR, bR); PRIO(0);
    VMW(4);        // gate: Ak0+Bk0 of tile t+1 resident
    BARX();
  }
  { // peeled last tile: no staging; epilogue drain vmcnt(0) before kk=1
    const int bb = (nk - 1) & 1;
    RDA(aR, 0, bb, 0); RDB(bR, 0, bb);
    BARX(); LGKM0();
    PRIO(1); MFMA16(0, aR, bR); PRIO(0);
    BARX();
    RDA(aR, 0, bb, 4);
    BARX(); LGKM0();
    PRIO(1); MFMA16(4, aR, bR); PRIO(0);
    VMW(0);
    BARX();
    RDA(aR, 1, bb, 0); RDB(bR, 1, bb);
    BARX(); LGKM0();
    PRIO(1); MFMA16(0, aR, bR); PRIO(0);
    BARX();
    RDA(aR, 1, bb, 4);
    BARX(); LGKM0();
    PRIO(1); MFMA16(4, aR, bR); PRIO(0);
    BARX();
  }

  // epilogue: direct scattered C write (same fragment->C map as gemm_bt)
  const int wr = (w >> 2) * 128, wc = (w & 3) * 64;
#pragma unroll
  for (int mi = 0; mi < 8; mi++) {
    const int row = m0 + wr + mi*16 + fg*4;
#pragma unroll
    for (int nj = 0; nj < 4; nj++) {
      const int col = n0 + wc + nj*16 + fr;
#pragma unroll
      for (int r = 0; r < 4; r++) {
        if (OUTMODE == 1) {
          ((float*)C)[(size_t)(row + r)*N + col] = acc[mi][nj][r];
        } else if (OUTMODE == 0) {
          ((unsigned short*)C)[(size_t)(row + r)*N + col] = f2bf(acc[mi][nj][r]);
        } else if (OUTMODE == 2) {
          const int rr = row + r;
          const int b = rr >> 11, s = rr & 2047;
          const int h = col >> 7, d = col & 127;
          ((unsigned short*)C)[(((size_t)(b*H_ + h) << 11) + s)*D_ + d] = f2bf(acc[mi][nj][r]);
        } else {   // OUTMODE == 3: fused QKV, outputs contiguous ELEMS apart
          const int rr = row + r;
          const int b = rr >> 11, s = rr & 2047;
          const int t = col >> 11;
          const int h = (col >> 7) & 15, d = col & 127;
          ((unsigned short*)C)[(size_t)t*ELEMS +
              (((size_t)(b*H_ + h) << 11) + s)*D_ + d] = f2bf(acc[mi][nj][r]);
        }
      }
    }
  }
#undef STG
#undef RDA
#undef RDB
#undef MFMA16
#undef BARX
#undef LGKM0
#undef VMW
#undef PRIO
}

// xpos rotary, in place on head-major bf16 Q and K [b,h,s,d].
__global__ __launch_bounds__(256)
void xpos_rotary(__hip_bfloat16* __restrict__ Q, __hip_bfloat16* __restrict__ Kt)
{
  const int idx = blockIdx.x * 256 + threadIdx.x;   // [0, B*H*S*64)
  const int j = idx & 63;
  const int s = (idx >> 6) & 2047;
  const float seq = (float)(s - 1024) * (1.0f/512.0f);
  const float dr = 2.0f + 2.0f*(float)j;
  const float theta = expf(dr * (1.0f/128.0f) * -9.210340371976184f);
  const float zeta  = (dr * (1.0f/64.0f) + 51.2f) * (1.0f/52.2f);
  const float ang = seq * theta;
  const float c  = cosf(ang);
  const float sn = sinf(ang);
  const float t  = expf(seq * logf(zeta));
  const float it = 1.0f / t;

  const size_t base = (size_t)(idx >> 6) * 128 + 2*j;
  unsigned short* Qs = (unsigned short*)Q;
  unsigned short* Ks = (unsigned short*)Kt;
  const float q0 = __bfloat162float(Q[base]),  q1 = __bfloat162float(Q[base+1]);
  Qs[base]   = f2bf((q0*c - q1*sn) * t);
  Qs[base+1] = f2bf((q1*c + q0*sn) * t);
  const float k0 = __bfloat162float(Kt[base]), k1 = __bfloat162float(Kt[base+1]);
  Ks[base]   = f2bf((k0*c - k1*sn) * it);
  Ks[base+1] = f2bf((k1*c + k0*sn) * it);
}

// Vh [b,h,s,d] bf16 -> VT3 packed f16:
// per (bh, kt=s/64) 16-KB tile, inner offset = d*64 + g*16 + half*8 + s1*4 + r
// where key=s%64 = (half*2+s1)*16 + g*4 + r.
__global__ __launch_bounds__(256)
void transpose_v(const __hip_bfloat16* __restrict__ Vh, _Float16* __restrict__ VT3)
{
  __shared__ float tile[32][33];
  const int tx = threadIdx.x, ty = threadIdx.y;      // block (32, 8)
  const int bh = blockIdx.z;
  const int s0 = blockIdx.x * 32, d0 = blockIdx.y * 32;
  const int kt = s0 >> 6, koff = s0 & 63;
#pragma unroll
  for (int r = 0; r < 4; r++) {
    const int s = s0 + ty + r*8;
    tile[ty + r*8][tx] = __bfloat162float(Vh[((size_t)bh*S_ + s)*D_ + d0 + tx]);
  }
  __syncthreads();
  const int key = koff + tx;
  const int g = (key >> 2) & 3, rr = key & 3, half = (key >> 5) & 1, s1 = (key >> 4) & 1;
  const size_t base = (size_t)bh*S_*D_ + (size_t)kt*8192 + g*16 + half*8 + s1*4 + rr;
#pragma unroll
  for (int r = 0; r < 4; r++) {
    const int d = d0 + ty + r*8;
    VT3[base + d*64] = (_Float16)tile[tx][ty + r*8];
  }
}

// Flash attention, causal (R1 structure: LDS-staged K/V via global_load_lds,
// 32-key double-buffered tiles shared by all 4 waves).
__global__ __launch_bounds__(256, 2)
void attn_fwd(const __hip_bfloat16* __restrict__ Qh,
              const __hip_bfloat16* __restrict__ Kh,
              const _Float16* __restrict__ VT3,
              __hip_bfloat16* __restrict__ O)
{
  __shared__ union {
    struct { unsigned short Kt[2][4096]; _Float16 Vt[2][4096]; } st;
    float ep[64*132];
  } sh;

  const int lane = threadIdx.x & 63;
  const int w    = threadIdx.x >> 6;
  const int L  = blockIdx.x;                   // 0..1023
  const int bh = (L & 7) + 8*((L >> 3) & 3);   // bh pinned to XCD = bh&7
  const int x  = 31 - (L >> 5);                // longest-first
  const int b = bh >> 4, h = bh & 15;
  const int q0 = x*64 + w*16;
  const int qc = lane & 15;
  const int g  = lane >> 4;
  const int qv = q0 + qc;

  const __hip_bfloat16* Kb = Kh + (size_t)bh*S_*D_;
  const _Float16* vtb = VT3 + (size_t)bh*S_*D_;

  const int kswz  = (qc & 7) << 4;                     // K read swizzle (bytes)
  const int vbase = qc*64 + ((g ^ ((qc >> 1) & 3)) << 4);  // V read base (bytes)

#define STAGE(BUF, P) do {                                                       \
    const int kb0_ = (P)*32;                                                     \
    _Pragma("unroll")                                                            \
    for (int ii = 0; ii < 2; ii++) {                                             \
      const int chunk = w*2 + ii;                                                \
      const int key   = chunk*4 + (lane >> 4);                                   \
      const int srcin = ((lane & 15)*16) ^ ((key & 7) << 4);                     \
      async_load16((const char*)Kb + (size_t)(kb0_ + key)*256 + srcin,           \
                   (char*)sh.st.Kt[BUF] + chunk*1024);                           \
    }                                                                            \
    const int kt_ = (P) >> 1, h_ = (P) & 1;                                      \
    _Pragma("unroll")                                                            \
    for (int ii = 0; ii < 2; ii++) {                                             \
      const int chunk = w*2 + ii;                                                \
      const int dd = chunk*16 + (lane >> 2);                                     \
      const int gg = (lane & 3) ^ ((lane >> 3) & 3);                             \
      async_load16((const char*)vtb + ((size_t)kt_*8192 + dd*64 + gg*16 + h_*8)*2,\
                   (char*)sh.st.Vt[BUF] + chunk*1024);                           \
    }                                                                            \
  } while (0)

#define COMPUTE(BUF, P) do {                                                     \
    const int k0_ = (P)*32;                                                      \
    const char* Kl = (const char*)sh.st.Kt[BUF];                                 \
    const char* Vl = (const char*)sh.st.Vt[BUF];                                 \
    bf16x8 ka[4], kbb[4]; f16x8 vv[8];                                           \
    _Pragma("unroll")                                                            \
    for (int c = 0; c < 4; c++) {                                                \
      const int off = (c*64 + g*16) ^ kswz;                                      \
      ka[c]  = *(const bf16x8*)(Kl + qc*256 + off);                              \
      kbb[c] = *(const bf16x8*)(Kl + (16 + qc)*256 + off);                       \
    }                                                                            \
    _Pragma("unroll")                                                            \
    for (int t = 0; t < 8; t++) vv[t] = *(const f16x8*)(Vl + t*1024 + vbase);    \
    f32x4 sA = (f32x4)0.0f, sB = (f32x4)0.0f;                                    \
    _Pragma("unroll")                                                            \
    for (int c = 0; c < 4; c++) {                                                \
      sA = __builtin_amdgcn_mfma_f32_16x16x32_bf16(ka[c],  qf[c], sA, 0, 0, 0);  \
      sB = __builtin_amdgcn_mfma_f32_16x16x32_bf16(kbb[c], qf[c], sB, 0, 0, 0);  \
    }                                                                            \
    float sv[8];                                                                 \
    _Pragma("unroll")                                                            \
    for (int r = 0; r < 4; r++) {                                                \
      sv[r]   = (k0_      + g*4 + r <= qv) ? sA[r]*scale : -1e30f;               \
      sv[4+r] = (k0_ + 16 + g*4 + r <= qv) ? sB[r]*scale : -1e30f;               \
    }                                                                            \
    float mx = sv[0];                                                            \
    _Pragma("unroll")                                                            \
    for (int j = 1; j < 8; j++) mx = fmaxf(mx, sv[j]);                           \
    mx = fmaxf(mx, __shfl_xor(mx, 16));                                          \
    mx = fmaxf(mx, __shfl_xor(mx, 32));                                          \
    const float m_new = fmaxf(m_i, mx);                                          \
    const float alpha = __expf(m_i - m_new);                                     \
    float p[8], ps = 0.0f;                                                       \
    _Pragma("unroll")                                                            \
    for (int j = 0; j < 8; j++) { p[j] = __expf(sv[j] - m_new); ps += p[j]; }    \
    ps += __shfl_xor(ps, 16);                                                    \
    ps += __shfl_xor(ps, 32);                                                    \
    l_i = l_i*alpha + ps;                                                        \
    m_i = m_new;                                                                 \
    f16x4 pA, pB;                                                                \
    _Pragma("unroll")                                                            \
    for (int r = 0; r < 4; r++) { pA[r] = (_Float16)p[r]; pB[r] = (_Float16)p[4+r]; } \
    _Pragma("unroll")                                                            \
    for (int t = 0; t < 8; t++) acc_o[t] *= alpha;                               \
    _Pragma("unroll")                                                            \
    for (int t = 0; t < 8; t++) {                                                \
      const f16x4 vA = __builtin_shufflevector(vv[t], vv[t], 0, 1, 2, 3);        \
      const f16x4 vB = __builtin_shufflevector(vv[t], vv[t], 4, 5, 6, 7);        \
      acc_o[t] = __builtin_amdgcn_mfma_f32_16x16x16f16(vA, pA, acc_o[t], 0, 0, 0); \
      acc_o[t] = __builtin_amdgcn_mfma_f32_16x16x16f16(vB, pB, acc_o[t], 0, 0, 0); \
    }                                                                            \
  } while (0)

  // issue tile-0 DMA first so it flies under the Q register loads
  STAGE(0, 0);

  bf16x8 qf[4];
  {
    const __hip_bfloat16* qrow = Qh + ((size_t)bh*S_ + qv)*D_ + g*8;
#pragma unroll
    for (int c = 0; c < 4; c++) qf[c] = *(const bf16x8*)(qrow + c*32);
  }

  f32x4 acc_o[8];
#pragma unroll
  for (int t = 0; t < 8; t++) acc_o[t] = (f32x4)0.0f;
  float m_i = -1e30f, l_i = 0.0f;
  const float scale = 0.08838834764831845f;   // 1/sqrt(128)

  const int ntile = 2*x + 2;       // 32-key tiles, uniform across the block

  __syncthreads();                 // drains vmcnt(0): tile 0 resident

  for (int p = 0; p < ntile; ++p) {
    if (p + 1 < ntile) STAGE((p + 1) & 1, p + 1);   // async prefetch
    COMPUTE(p & 1, p);
    __syncthreads();               // drain: tile p+1 resident, buf p free
  }

  // epilogue: O^T[d][q] -> LDS as O[q][d] (stride 132), coalesced bf16 store.
  const float inv_l = 1.0f / l_i;
#pragma unroll
  for (int t = 0; t < 8; t++)
#pragma unroll
    for (int r = 0; r < 4; r++)
      sh.ep[(w*16 + qc)*132 + t*16 + g*4 + r] = acc_o[t][r] * inv_l;
  __syncthreads();

  const int row = threadIdx.x >> 2;          // 0..63
  const int c0  = (threadIdx.x & 3) * 32;
  unsigned short* Os = (unsigned short*)O;
  const size_t obase = ((size_t)b*S_ + x*64 + row)*E_ + h*D_;
#pragma unroll
  for (int i = 0; i < 8; i++) {
    const f32x4 v4 = *(const f32x4*)(sh.ep + row*132 + c0 + i*4);
    u16x4 o4;
    o4.x = f2bf(v4.x); o4.y = f2bf(v4.y); o4.z = f2bf(v4.z); o4.w = f2bf(v4.w);
    *(u16x4*)(Os + obase + c0 + i*4) = o4;
  }
#undef STAGE
#undef COMPUTE
}

extern "C" void kernel_launch(void* const* d_in, const int* in_sizes, int n_in,
                              void* d_out, int out_size, void* d_ws, size_t ws_size,
                              hipStream_t stream)
{
  (void)in_sizes; (void)n_in; (void)out_size; (void)ws_size;
  const float* act = (const float*)d_in[0];
  const float* Wq  = (const float*)d_in[1];
  const float* Wk  = (const float*)d_in[2];
  const float* Wv  = (const float*)d_in[3];
  const float* Wo  = (const float*)d_in[4];

  __hip_bfloat16* actb = (__hip_bfloat16*)d_ws;
  __hip_bfloat16* Wqb  = actb + ELEMS;
  __hip_bfloat16* Wkb  = Wqb + WELEMS;
  __hip_bfloat16* Wvb  = Wkb + WELEMS;
  __hip_bfloat16* Wob  = Wvb + WELEMS;
  __hip_bfloat16* Q    = Wob + WELEMS;
  __hip_bfloat16* Kp   = Q + ELEMS;
  __hip_bfloat16* V    = Kp + ELEMS;
  _Float16*       VT   = (_Float16*)(V + ELEMS);
  __hip_bfloat16* AO   = V;   // V dead after transpose_v; reuse for attn output

  cvt_f32_bf16<<<ELEMS/4/256, 256, 0, stream>>>(act, (unsigned short*)actb, ELEMS/4);
  cvt4_f32_bf16<<<dim3(WELEMS/4/256, 4), 256, 0, stream>>>(
      Wq, Wk, Wv, Wo,
      (unsigned short*)Wqb, (unsigned short*)Wkb,
      (unsigned short*)Wvb, (unsigned short*)Wob, WELEMS/4);

  // Fused QKV projection: one [4096 x 6144 x 2048] GEMM on the 256^2 8-phase
  // kernel; grid = 16*24 = 384 blocks (%8==0 for the XCD swizzle), 128 KiB LDS.
  gemm_bt8<3><<<(B_*S_/256)*(3*E_/256), 512, 131072, stream>>>(
      actb, Wqb, Q, B_*S_, 3*E_, E_);

  xpos_rotary<<<(B_*S_*H_*64)/256, 256, 0, stream>>>(Q, Kp);
  transpose_v<<<dim3(S_/32, D_/32, B_*H_), dim3(32, 8), 0, stream>>>(V, VT);
  attn_fwd<<<1024, 256, 0, stream>>>(Q, Kp, VT, AO);

  const dim3 gg(E_/128, (B_*S_)/128);
  gemm_bt<1><<<gg, 256, 0, stream>>>(AO, Wob, d_out, B_*S_, E_, E_);
}

// Round 4
// 410.395 us; speedup vs baseline: 1.4259x; 1.0024x over previous
//
#include <hip/hip_runtime.h>
#include <hip/hip_bf16.h>

typedef __attribute__((ext_vector_type(8))) short bf16x8;
typedef __attribute__((ext_vector_type(4))) float f32x4;
typedef __attribute__((ext_vector_type(4))) _Float16 f16x4;
typedef __attribute__((ext_vector_type(8))) _Float16 f16x8;
typedef __attribute__((ext_vector_type(4))) unsigned short u16x4;

#define B_ 2
#define S_ 2048
#define E_ 2048
#define H_ 16
#define D_ 128
#define ELEMS (B_*S_*E_)   // 8388608 elements of [B,S,2048]
#define WELEMS (E_*E_)     // 4194304 elements per weight matrix

__device__ __forceinline__ unsigned short f2bf(float x) {
  unsigned int u = __float_as_uint(x);
  u += 0x7fffu + ((u >> 16) & 1u);
  return (unsigned short)(u >> 16);
}

__device__ __forceinline__ void async_load16(const void* g, void* l) {
  __builtin_amdgcn_global_load_lds(
      (const __attribute__((address_space(1))) unsigned int*)g,
      (__attribute__((address_space(3))) unsigned int*)l, 16, 0, 0);
}

// f32 -> bf16 (RNE), vectorized x4. n4 = n/4.
__global__ __launch_bounds__(256)
void cvt_f32_bf16(const float* __restrict__ src, unsigned short* __restrict__ dst, int n4)
{
  const int i = blockIdx.x * 256 + threadIdx.x;
  if (i < n4) {
    const f32x4 v = ((const f32x4*)src)[i];
    u16x4 o;
    o.x = f2bf(v.x); o.y = f2bf(v.y); o.z = f2bf(v.z); o.w = f2bf(v.w);
    ((u16x4*)dst)[i] = o;
  }
}

// four equally-sized weight tensors in one launch (blockIdx.y selects)
__global__ __launch_bounds__(256)
void cvt4_f32_bf16(const float* __restrict__ s0, const float* __restrict__ s1,
                   const float* __restrict__ s2, const float* __restrict__ s3,
                   unsigned short* __restrict__ d0, unsigned short* __restrict__ d1,
                   unsigned short* __restrict__ d2, unsigned short* __restrict__ d3,
                   int n4)
{
  const int i = blockIdx.x * 256 + threadIdx.x;
  if (i >= n4) return;
  const float* s; unsigned short* d;
  switch (blockIdx.y) {
    case 0: s = s0; d = d0; break;
    case 1: s = s1; d = d1; break;
    case 2: s = s2; d = d2; break;
    default: s = s3; d = d3; break;
  }
  const f32x4 v = ((const f32x4*)s)[i];
  u16x4 o;
  o.x = f2bf(v.x); o.y = f2bf(v.y); o.z = f2bf(v.z); o.w = f2bf(v.w);
  ((u16x4*)d)[i] = o;
}

// ---------------------------------------------------------------------------
// Legacy 128x128 GEMM (m97 structure) - retained for the Wo projection where
// the 256^2 kernel would only fill 128 of 256 CUs.
template<int OUTMODE>
__global__ __launch_bounds__(256)
void gemm_bt(const __hip_bfloat16* __restrict__ A,
             const __hip_bfloat16* __restrict__ Bw,
             void* __restrict__ C, int M, int N, int K)
{
  __shared__ __hip_bfloat16 As[128*32];
  __shared__ __hip_bfloat16 Bs[128*32];
  const int tid  = threadIdx.x;
  const int lane = tid & 63;
  const int w    = tid >> 6;
  const int m0 = blockIdx.y * 128;
  const int n0 = blockIdx.x * 128;
  const int wm = (w >> 1) * 64;
  const int wn = (w & 1) * 64;
  const int lrow = lane >> 2;
  const int lcol = (lane & 3) * 8;
  const int fr = lane & 15;
  const int fg = lane >> 4;

  f32x4 acc[4][4];
#pragma unroll
  for (int i = 0; i < 4; i++)
#pragma unroll
    for (int j = 0; j < 4; j++) acc[i][j] = (f32x4)0.0f;

  for (int k0 = 0; k0 < K; k0 += 32) {
    __syncthreads();
#pragma unroll
    for (int s = 0; s < 2; s++) {
      const int rbase = s*64 + w*16;
      async_load16(A  + (size_t)(m0 + rbase + lrow)*K + k0 + lcol, As + rbase*32);
      async_load16(Bw + (size_t)(n0 + rbase + lrow)*K + k0 + lcol, Bs + rbase*32);
    }
    __syncthreads();
    bf16x8 af[4], bfr[4];
#pragma unroll
    for (int i = 0; i < 4; i++) {
      af[i]  = *(const bf16x8*)(As + (wm + i*16 + fr)*32 + fg*8);
      bfr[i] = *(const bf16x8*)(Bs + (wn + i*16 + fr)*32 + fg*8);
    }
#pragma unroll
    for (int i = 0; i < 4; i++)
#pragma unroll
      for (int j = 0; j < 4; j++)
        acc[i][j] = __builtin_amdgcn_mfma_f32_16x16x32_bf16(af[i], bfr[j], acc[i][j], 0, 0, 0);
  }

#pragma unroll
  for (int i = 0; i < 4; i++) {
    const int row = m0 + wm + i*16 + fg*4;
#pragma unroll
    for (int j = 0; j < 4; j++) {
      const int col = n0 + wn + j*16 + fr;
#pragma unroll
      for (int r = 0; r < 4; r++) {
        if (OUTMODE == 1) {
          ((float*)C)[(size_t)(row + r)*N + col] = acc[i][j][r];
        } else if (OUTMODE == 0) {
          ((unsigned short*)C)[(size_t)(row + r)*N + col] = f2bf(acc[i][j][r]);
        } else if (OUTMODE == 2) {
          const int rr = row + r;
          const int b = rr >> 11, s = rr & 2047;
          const int h = col >> 7, d = col & 127;
          ((unsigned short*)C)[(((size_t)(b*H_ + h) << 11) + s)*D_ + d] = f2bf(acc[i][j][r]);
        } else {
          const int rr = row + r;
          const int b = rr >> 11, s = rr & 2047;
          const int t = col >> 11;
          const int h = (col >> 7) & 15, d = col & 127;
          ((unsigned short*)C)[(size_t)t*ELEMS +
              (((size_t)(b*H_ + h) << 11) + s)*D_ + d] = f2bf(acc[i][j][r]);
        }
      }
    }
  }
}

// ---------------------------------------------------------------------------
// 256x256-tile 8-phase GEMM (HK-style schedule, plain HIP). 512 threads =
// 8 waves (2M x 4N), per-wave output 128x64, BK=64 split into two k-halves.
// LDS ring: 2 buffers x {A[2][256][32], B[2][256][32]} bf16 = 128 KiB.
// Swizzle (R3 fix): 16B-slot ^= (row>>1)&3. Row stride = 64B = 16 banks, so
// bank window = (row&1, slot); (row>>1)&3 walks the 4 slots across rows 0..7
// giving each of the 8 windows exactly 2 hits per 16 rows (2-way = free).
// The old (row&3) key left rows {0,4,8,12} on identical banks -> 4-way
// conflict, 9.4M SQ_LDS_BANK_CONFLICT, MfmaUtil capped at 30%.
// DMA dest linear; inverse swizzle pre-applied on per-lane global source.
template<int OUTMODE>
__global__ __launch_bounds__(512, 2)
void gemm_bt8(const __hip_bfloat16* __restrict__ A,
              const __hip_bfloat16* __restrict__ Bw,
              void* __restrict__ C, int M, int N, int K)
{
  extern __shared__ char lds[];
  const int tid  = threadIdx.x;
  const int lane = tid & 63;
  const int w    = tid >> 6;        // 0..7
  const int fr   = lane & 15;
  const int fg   = lane >> 4;       // 0..3

  // XCD-aware swizzle of the linear block id (grid % 8 == 0)
  const int nblk = N >> 8;
  const int cpx  = gridDim.x >> 3;
  const int lin  = blockIdx.x;
  const int swz  = (lin & 7) * cpx + (lin >> 3);
  const int m0 = (swz / nblk) << 8;
  const int n0 = (swz % nblk) << 8;

  // LDS read geometry: addr = buf*65536 + (B?32768:0) + kk*16384
  //                  + row*64 + ((slot ^ ((row>>1)&3))<<4); fragment row
  //                  offset fr is base-independent (bases are mult of 16).
  const int Ssw = (fg ^ ((fr >> 1) & 3)) << 4;
  const int pA  = ((w >> 2) * 128 + fr) * 64 + Ssw;   // + mi*1024
  const int pB  = 32768 + ((w & 3) * 64 + fr) * 64 + Ssw;

  // Staging geometry: per stage-unit (one operand, one k-half: 256 rows x 32k
  // = 16 KB) each thread issues 2 DMAs. Dest row = chunk*16 + (lane>>2),
  // stored slot = lane&3; source k-group = (lane&3) ^ ((row>>1)&3) where
  // (row>>1)&3 == (lane>>3)&3 (chunk*8 is a multiple of 4).
  const int r0 = w * 32 + (lane >> 2);                 // row for ii=0; ii=1: +16
  const int ks = ((lane & 3) ^ ((lane >> 3) & 3)) * 8; // source k offset (elems)
  const __hip_bfloat16* Asrc = A  + (size_t)(m0 + r0) * K + ks;
  const __hip_bfloat16* Bsrc = Bw + (size_t)(n0 + r0) * K + ks;
  const int dgrp = w * 2048;                           // (w*2)*1024 dest base

#define STG(NB, OPB, KH, KT) do {                                              \
    const size_t ko_ = (size_t)(KT)*64 + (KH)*32;                              \
    const __hip_bfloat16* sp_ = (OPB) ? Bsrc : Asrc;                           \
    char* dp_ = lds + (NB)*65536 + (OPB)*32768 + (KH)*16384 + dgrp;            \
    async_load16(sp_ + ko_, dp_);                                              \
    async_load16(sp_ + (size_t)16*K + ko_, dp_ + 1024);                        \
  } while (0)

#define RDA(DST, KK, BB, MI0) do {                                             \
    const char* p_ = lds + (BB)*65536 + (KK)*16384 + pA + (MI0)*1024;          \
    DST[0] = *(const bf16x8*)(p_);                                             \
    DST[1] = *(const bf16x8*)(p_ + 1024);                                      \
    DST[2] = *(const bf16x8*)(p_ + 2048);                                      \
    DST[3] = *(const bf16x8*)(p_ + 3072);                                      \
  } while (0)

#define RDB(DST, KK, BB) do {                                                  \
    const char* p_ = lds + (BB)*65536 + (KK)*16384 + pB;                       \
    DST[0] = *(const bf16x8*)(p_);                                             \
    DST[1] = *(const bf16x8*)(p_ + 1024);                                      \
    DST[2] = *(const bf16x8*)(p_ + 2048);                                      \
    DST[3] = *(const bf16x8*)(p_ + 3072);                                      \
  } while (0)

#define MFMA16(MI0, AR, BR)                                                    \
    _Pragma("unroll")                                                          \
    for (int i_ = 0; i_ < 4; i_++)                                             \
    _Pragma("unroll")                                                          \
    for (int j_ = 0; j_ < 4; j_++)                                             \
      acc[(MI0)+i_][j_] = __builtin_amdgcn_mfma_f32_16x16x32_bf16(             \
          AR[i_], BR[j_], acc[(MI0)+i_][j_], 0, 0, 0)

#define BARX() __builtin_amdgcn_s_barrier()
#define LGKM0() do { asm volatile("s_waitcnt lgkmcnt(0)" ::: "memory");        \
                     __builtin_amdgcn_sched_barrier(0); } while (0)
#define VMW(NN) asm volatile("s_waitcnt vmcnt(" #NN ")" ::: "memory")
#define PRIO(P) __builtin_amdgcn_s_setprio(P)

  f32x4 acc[8][4];
#pragma unroll
  for (int i = 0; i < 8; i++)
#pragma unroll
    for (int j = 0; j < 4; j++) acc[i][j] = (f32x4)0.0f;

  // prologue: stage tile 0 (units Ak0, Bk0, Ak1, Bk1) into buffer 0
  STG(0, 0, 0, 0);
  STG(0, 1, 0, 0);
  STG(0, 0, 1, 0);
  STG(0, 1, 1, 0);
  VMW(4);          // Ak0+Bk0 of tile 0 resident (Ak1/Bk1 still in flight)
  BARX();

  const int nk = K >> 6;   // K-tiles of 64
  bf16x8 aR[4], bR[4];

  for (int t = 0; t < nk - 1; ++t) {
    const int bb = t & 1, nb = bb ^ 1;
    // P0: kk=0, M-quads 0-1
    RDA(aR, 0, bb, 0); RDB(bR, 0, bb);
    STG(nb, 0, 0, t + 1);
    BARX(); LGKM0();
    PRIO(1); MFMA16(0, aR, bR); PRIO(0);
    BARX();
    // P1: kk=0, M-quads 2-3
    RDA(aR, 0, bb, 4);
    STG(nb, 1, 0, t + 1);
    BARX(); LGKM0();
    PRIO(1); MFMA16(4, aR, bR); PRIO(0);
    VMW(4);        // gate: Ak1+Bk1 of tile t resident
    BARX();
    // P2: kk=1, M-quads 0-1
    RDA(aR, 1, bb, 0); RDB(bR, 1, bb);
    STG(nb, 0, 1, t + 1);
    BARX(); LGKM0();
    PRIO(1); MFMA16(0, aR, bR); PRIO(0);
    BARX();
    // P3: kk=1, M-quads 2-3
    RDA(aR, 1, bb, 4);
    STG(nb, 1, 1, t + 1);
    BARX(); LGKM0();
    PRIO(1); MFMA16(4, aR, bR); PRIO(0);
    VMW(4);        // gate: Ak0+Bk0 of tile t+1 resident
    BARX();
  }
  { // peeled last tile: no staging; epilogue drain vmcnt(0) before kk=1
    const int bb = (nk - 1) & 1;
    RDA(aR, 0, bb, 0); RDB(bR, 0, bb);
    BARX(); LGKM0();
    PRIO(1); MFMA16(0, aR, bR); PRIO(0);
    BARX();
    RDA(aR, 0, bb, 4);
    BARX(); LGKM0();
    PRIO(1); MFMA16(4, aR, bR); PRIO(0);
    VMW(0);
    BARX();
    RDA(aR, 1, bb, 0); RDB(bR, 1, bb);
    BARX(); LGKM0();
    PRIO(1); MFMA16(0, aR, bR); PRIO(0);
    BARX();
    RDA(aR, 1, bb, 4);
    BARX(); LGKM0();
    PRIO(1); MFMA16(4, aR, bR); PRIO(0);
    BARX();
  }

  // epilogue: direct scattered C write (same fragment->C map as gemm_bt)
  const int wr = (w >> 2) * 128, wc = (w & 3) * 64;
#pragma unroll
  for (int mi = 0; mi < 8; mi++) {
    const int row = m0 + wr + mi*16 + fg*4;
#pragma unroll
    for (int nj = 0; nj < 4; nj++) {
      const int col = n0 + wc + nj*16 + fr;
#pragma unroll
      for (int r = 0; r < 4; r++) {
        if (OUTMODE == 1) {
          ((float*)C)[(size_t)(row + r)*N + col] = acc[mi][nj][r];
        } else if (OUTMODE == 0) {
          ((unsigned short*)C)[(size_t)(row + r)*N + col] = f2bf(acc[mi][nj][r]);
        } else if (OUTMODE == 2) {
          const int rr = row + r;
          const int b = rr >> 11, s = rr & 2047;
          const int h = col >> 7, d = col & 127;
          ((unsigned short*)C)[(((size_t)(b*H_ + h) << 11) + s)*D_ + d] = f2bf(acc[mi][nj][r]);
        } else {   // OUTMODE == 3: fused QKV, outputs contiguous ELEMS apart
          const int rr = row + r;
          const int b = rr >> 11, s = rr & 2047;
          const int t = col >> 11;
          const int h = (col >> 7) & 15, d = col & 127;
          ((unsigned short*)C)[(size_t)t*ELEMS +
              (((size_t)(b*H_ + h) << 11) + s)*D_ + d] = f2bf(acc[mi][nj][r]);
        }
      }
    }
  }
#undef STG
#undef RDA
#undef RDB
#undef MFMA16
#undef BARX
#undef LGKM0
#undef VMW
#undef PRIO
}

// xpos rotary, in place on head-major bf16 Q and K [b,h,s,d].
__global__ __launch_bounds__(256)
void xpos_rotary(__hip_bfloat16* __restrict__ Q, __hip_bfloat16* __restrict__ Kt)
{
  const int idx = blockIdx.x * 256 + threadIdx.x;   // [0, B*H*S*64)
  const int j = idx & 63;
  const int s = (idx >> 6) & 2047;
  const float seq = (float)(s - 1024) * (1.0f/512.0f);
  const float dr = 2.0f + 2.0f*(float)j;
  const float theta = expf(dr * (1.0f/128.0f) * -9.210340371976184f);
  const float zeta  = (dr * (1.0f/64.0f) + 51.2f) * (1.0f/52.2f);
  const float ang = seq * theta;
  const float c  = cosf(ang);
  const float sn = sinf(ang);
  const float t  = expf(seq * logf(zeta));
  const float it = 1.0f / t;

  const size_t base = (size_t)(idx >> 6) * 128 + 2*j;
  unsigned short* Qs = (unsigned short*)Q;
  unsigned short* Ks = (unsigned short*)Kt;
  const float q0 = __bfloat162float(Q[base]),  q1 = __bfloat162float(Q[base+1]);
  Qs[base]   = f2bf((q0*c - q1*sn) * t);
  Qs[base+1] = f2bf((q1*c + q0*sn) * t);
  const float k0 = __bfloat162float(Kt[base]), k1 = __bfloat162float(Kt[base+1]);
  Ks[base]   = f2bf((k0*c - k1*sn) * it);
  Ks[base+1] = f2bf((k1*c + k0*sn) * it);
}

// Vh [b,h,s,d] bf16 -> VT3 packed f16:
// per (bh, kt=s/64) 16-KB tile, inner offset = d*64 + g*16 + half*8 + s1*4 + r
// where key=s%64 = (half*2+s1)*16 + g*4 + r.
__global__ __launch_bounds__(256)
void transpose_v(const __hip_bfloat16* __restrict__ Vh, _Float16* __restrict__ VT3)
{
  __shared__ float tile[32][33];
  const int tx = threadIdx.x, ty = threadIdx.y;      // block (32, 8)
  const int bh = blockIdx.z;
  const int s0 = blockIdx.x * 32, d0 = blockIdx.y * 32;
  const int kt = s0 >> 6, koff = s0 & 63;
#pragma unroll
  for (int r = 0; r < 4; r++) {
    const int s = s0 + ty + r*8;
    tile[ty + r*8][tx] = __bfloat162float(Vh[((size_t)bh*S_ + s)*D_ + d0 + tx]);
  }
  __syncthreads();
  const int key = koff + tx;
  const int g = (key >> 2) & 3, rr = key & 3, half = (key >> 5) & 1, s1 = (key >> 4) & 1;
  const size_t base = (size_t)bh*S_*D_ + (size_t)kt*8192 + g*16 + half*8 + s1*4 + rr;
#pragma unroll
  for (int r = 0; r < 4; r++) {
    const int d = d0 + ty + r*8;
    VT3[base + d*64] = (_Float16)tile[tx][ty + r*8];
  }
}

// Flash attention, causal (R1 structure: LDS-staged K/V via global_load_lds,
// 32-key double-buffered tiles shared by all 4 waves).
__global__ __launch_bounds__(256, 2)
void attn_fwd(const __hip_bfloat16* __restrict__ Qh,
              const __hip_bfloat16* __restrict__ Kh,
              const _Float16* __restrict__ VT3,
              __hip_bfloat16* __restrict__ O)
{
  __shared__ union {
    struct { unsigned short Kt[2][4096]; _Float16 Vt[2][4096]; } st;
    float ep[64*132];
  } sh;

  const int lane = threadIdx.x & 63;
  const int w    = threadIdx.x >> 6;
  const int L  = blockIdx.x;                   // 0..1023
  const int bh = (L & 7) + 8*((L >> 3) & 3);   // bh pinned to XCD = bh&7
  const int x  = 31 - (L >> 5);                // longest-first
  const int b = bh >> 4, h = bh & 15;
  const int q0 = x*64 + w*16;
  const int qc = lane & 15;
  const int g  = lane >> 4;
  const int qv = q0 + qc;

  const __hip_bfloat16* Kb = Kh + (size_t)bh*S_*D_;
  const _Float16* vtb = VT3 + (size_t)bh*S_*D_;

  const int kswz  = (qc & 7) << 4;                     // K read swizzle (bytes)
  const int vbase = qc*64 + ((g ^ ((qc >> 1) & 3)) << 4);  // V read base (bytes)

#define STAGE(BUF, P) do {                                                       \
    const int kb0_ = (P)*32;                                                     \
    _Pragma("unroll")                                                            \
    for (int ii = 0; ii < 2; ii++) {                                             \
      const int chunk = w*2 + ii;                                                \
      const int key   = chunk*4 + (lane >> 4);                                   \
      const int srcin = ((lane & 15)*16) ^ ((key & 7) << 4);                     \
      async_load16((const char*)Kb + (size_t)(kb0_ + key)*256 + srcin,           \
                   (char*)sh.st.Kt[BUF] + chunk*1024);                           \
    }                                                                            \
    const int kt_ = (P) >> 1, h_ = (P) & 1;                                      \
    _Pragma("unroll")                                                            \
    for (int ii = 0; ii < 2; ii++) {                                             \
      const int chunk = w*2 + ii;                                                \
      const int dd = chunk*16 + (lane >> 2);                                     \
      const int gg = (lane & 3) ^ ((lane >> 3) & 3);                             \
      async_load16((const char*)vtb + ((size_t)kt_*8192 + dd*64 + gg*16 + h_*8)*2,\
                   (char*)sh.st.Vt[BUF] + chunk*1024);                           \
    }                                                                            \
  } while (0)

#define COMPUTE(BUF, P) do {                                                     \
    const int k0_ = (P)*32;                                                      \
    const char* Kl = (const char*)sh.st.Kt[BUF];                                 \
    const char* Vl = (const char*)sh.st.Vt[BUF];                                 \
    bf16x8 ka[4], kbb[4]; f16x8 vv[8];                                           \
    _Pragma("unroll")                                                            \
    for (int c = 0; c < 4; c++) {                                                \
      const int off = (c*64 + g*16) ^ kswz;                                      \
      ka[c]  = *(const bf16x8*)(Kl + qc*256 + off);                              \
      kbb[c] = *(const bf16x8*)(Kl + (16 + qc)*256 + off);                       \
    }                                                                            \
    _Pragma("unroll")                                                            \
    for (int t = 0; t < 8; t++) vv[t] = *(const f16x8*)(Vl + t*1024 + vbase);    \
    f32x4 sA = (f32x4)0.0f, sB = (f32x4)0.0f;                                    \
    _Pragma("unroll")                                                            \
    for (int c = 0; c < 4; c++) {                                                \
      sA = __builtin_amdgcn_mfma_f32_16x16x32_bf16(ka[c],  qf[c], sA, 0, 0, 0);  \
      sB = __builtin_amdgcn_mfma_f32_16x16x32_bf16(kbb[c], qf[c], sB, 0, 0, 0);  \
    }                                                                            \
    float sv[8];                                                                 \
    _Pragma("unroll")                                                            \
    for (int r = 0; r < 4; r++) {                                                \
      sv[r]   = (k0_      + g*4 + r <= qv) ? sA[r]*scale : -1e30f;               \
      sv[4+r] = (k0_ + 16 + g*4 + r <= qv) ? sB[r]*scale : -1e30f;               \
    }                                                                            \
    float mx = sv[0];                                                            \
    _Pragma("unroll")                                                            \
    for (int j = 1; j < 8; j++) mx = fmaxf(mx, sv[j]);                           \
    mx = fmaxf(mx, __shfl_xor(mx, 16));                                          \
    mx = fmaxf(mx, __shfl_xor(mx, 32));                                          \
    const float m_new = fmaxf(m_i, mx);                                          \
    const float alpha = __expf(m_i - m_new);                                     \
    float p[8], ps = 0.0f;                                                       \
    _Pragma("unroll")                                                            \
    for (int j = 0; j < 8; j++) { p[j] = __expf(sv[j] - m_new); ps += p[j]; }    \
    ps += __shfl_xor(ps, 16);                                                    \
    ps += __shfl_xor(ps, 32);                                                    \
    l_i = l_i*alpha + ps;                                                        \
    m_i = m_new;                                                                 \
    f16x4 pA, pB;                                                                \
    _Pragma("unroll")                                                            \
    for (int r = 0; r < 4; r++) { pA[r] = (_Float16)p[r]; pB[r] = (_Float16)p[4+r]; } \
    _Pragma("unroll")                                                            \
    for (int t = 0; t < 8; t++) acc_o[t] *= alpha;                               \
    _Pragma("unroll")                                                            \
    for (int t = 0; t < 8; t++) {                                                \
      const f16x4 vA = __builtin_shufflevector(vv[t], vv[t], 0, 1, 2, 3);        \
      const f16x4 vB = __builtin_shufflevector(vv[t], vv[t], 4, 5, 6, 7);        \
      acc_o[t] = __builtin_amdgcn_mfma_f32_16x16x16f16(vA, pA, acc_o[t], 0, 0, 0); \
      acc_o[t] = __builtin_amdgcn_mfma_f32_16x16x16f16(vB, pB, acc_o[t], 0, 0, 0); \
    }                                                                            \
  } while (0)

  // issue tile-0 DMA first so it flies under the Q register loads
  STAGE(0, 0);

  bf16x8 qf[4];
  {
    const __hip_bfloat16* qrow = Qh + ((size_t)bh*S_ + qv)*D_ + g*8;
#pragma unroll
    for (int c = 0; c < 4; c++) qf[c] = *(const bf16x8*)(qrow + c*32);
  }

  f32x4 acc_o[8];
#pragma unroll
  for (int t = 0; t < 8; t++) acc_o[t] = (f32x4)0.0f;
  float m_i = -1e30f, l_i = 0.0f;
  const float scale = 0.08838834764831845f;   // 1/sqrt(128)

  const int ntile = 2*x + 2;       // 32-key tiles, uniform across the block

  __syncthreads();                 // drains vmcnt(0): tile 0 resident

  for (int p = 0; p < ntile; ++p) {
    if (p + 1 < ntile) STAGE((p + 1) & 1, p + 1);   // async prefetch
    COMPUTE(p & 1, p);
    __syncthreads();               // drain: tile p+1 resident, buf p free
  }

  // epilogue: O^T[d][q] -> LDS as O[q][d] (stride 132), coalesced bf16 store.
  const float inv_l = 1.0f / l_i;
#pragma unroll
  for (int t = 0; t < 8; t++)
#pragma unroll
    for (int r = 0; r < 4; r++)
      sh.ep[(w*16 + qc)*132 + t*16 + g*4 + r] = acc_o[t][r] * inv_l;
  __syncthreads();

  const int row = threadIdx.x >> 2;          // 0..63
  const int c0  = (threadIdx.x & 3) * 32;
  unsigned short* Os = (unsigned short*)O;
  const size_t obase = ((size_t)b*S_ + x*64 + row)*E_ + h*D_;
#pragma unroll
  for (int i = 0; i < 8; i++) {
    const f32x4 v4 = *(const f32x4*)(sh.ep + row*132 + c0 + i*4);
    u16x4 o4;
    o4.x = f2bf(v4.x); o4.y = f2bf(v4.y); o4.z = f2bf(v4.z); o4.w = f2bf(v4.w);
    *(u16x4*)(Os + obase + c0 + i*4) = o4;
  }
#undef STAGE
#undef COMPUTE
}

extern "C" void kernel_launch(void* const* d_in, const int* in_sizes, int n_in,
                              void* d_out, int out_size, void* d_ws, size_t ws_size,
                              hipStream_t stream)
{
  (void)in_sizes; (void)n_in; (void)out_size; (void)ws_size;
  const float* act = (const float*)d_in[0];
  const float* Wq  = (const float*)d_in[1];
  const float* Wk  = (const float*)d_in[2];
  const float* Wv  = (const float*)d_in[3];
  const float* Wo  = (const float*)d_in[4];

  __hip_bfloat16* actb = (__hip_bfloat16*)d_ws;
  __hip_bfloat16* Wqb  = actb + ELEMS;
  __hip_bfloat16* Wkb  = Wqb + WELEMS;
  __hip_bfloat16* Wvb  = Wkb + WELEMS;
  __hip_bfloat16* Wob  = Wvb + WELEMS;
  __hip_bfloat16* Q    = Wob + WELEMS;
  __hip_bfloat16* Kp   = Q + ELEMS;
  __hip_bfloat16* V    = Kp + ELEMS;
  _Float16*       VT   = (_Float16*)(V + ELEMS);
  __hip_bfloat16* AO   = V;   // V dead after transpose_v; reuse for attn output

  cvt_f32_bf16<<<ELEMS/4/256, 256, 0, stream>>>(act, (unsigned short*)actb, ELEMS/4);
  cvt4_f32_bf16<<<dim3(WELEMS/4/256, 4), 256, 0, stream>>>(
      Wq, Wk, Wv, Wo,
      (unsigned short*)Wqb, (unsigned short*)Wkb,
      (unsigned short*)Wvb, (unsigned short*)Wob, WELEMS/4);

  // Fused QKV projection: one [4096 x 6144 x 2048] GEMM on the 256^2 8-phase
  // kernel; grid = 16*24 = 384 blocks (%8==0 for the XCD swizzle), 128 KiB LDS.
  gemm_bt8<3><<<(B_*S_/256)*(3*E_/256), 512, 131072, stream>>>(
      actb, Wqb, Q, B_*S_, 3*E_, E_);

  xpos_rotary<<<(B_*S_*H_*64)/256, 256, 0, stream>>>(Q, Kp);
  transpose_v<<<dim3(S_/32, D_/32, B_*H_), dim3(32, 8), 0, stream>>>(V, VT);
  attn_fwd<<<1024, 256, 0, stream>>>(Q, Kp, VT, AO);

  const dim3 gg(E_/128, (B_*S_)/128);
  gemm_bt<1><<<gg, 256, 0, stream>>>(AO, Wob, d_out, B_*S_, E_, E_);
}

// Round 5
// 400.084 us; speedup vs baseline: 1.4627x; 1.0258x over previous
//
#include <hip/hip_runtime.h>
#include <hip/hip_bf16.h>

typedef __attribute__((ext_vector_type(8))) short bf16x8;
typedef __attribute__((ext_vector_type(4))) float f32x4;
typedef __attribute__((ext_vector_type(4))) _Float16 f16x4;
typedef __attribute__((ext_vector_type(8))) _Float16 f16x8;
typedef __attribute__((ext_vector_type(4))) unsigned short u16x4;

#define B_ 2
#define S_ 2048
#define E_ 2048
#define H_ 16
#define D_ 128
#define ELEMS (B_*S_*E_)   // 8388608 elements of [B,S,2048]
#define WELEMS (E_*E_)     // 4194304 elements per weight matrix

__device__ __forceinline__ unsigned short f2bf(float x) {
  unsigned int u = __float_as_uint(x);
  u += 0x7fffu + ((u >> 16) & 1u);
  return (unsigned short)(u >> 16);
}

__device__ __forceinline__ void async_load16(const void* g, void* l) {
  __builtin_amdgcn_global_load_lds(
      (const __attribute__((address_space(1))) unsigned int*)g,
      (__attribute__((address_space(3))) unsigned int*)l, 16, 0, 0);
}

// f32 -> bf16 (RNE), vectorized x4. n4 = n/4.
__global__ __launch_bounds__(256)
void cvt_f32_bf16(const float* __restrict__ src, unsigned short* __restrict__ dst, int n4)
{
  const int i = blockIdx.x * 256 + threadIdx.x;
  if (i < n4) {
    const f32x4 v = ((const f32x4*)src)[i];
    u16x4 o;
    o.x = f2bf(v.x); o.y = f2bf(v.y); o.z = f2bf(v.z); o.w = f2bf(v.w);
    ((u16x4*)dst)[i] = o;
  }
}

// four equally-sized weight tensors in one launch (blockIdx.y selects)
__global__ __launch_bounds__(256)
void cvt4_f32_bf16(const float* __restrict__ s0, const float* __restrict__ s1,
                   const float* __restrict__ s2, const float* __restrict__ s3,
                   unsigned short* __restrict__ d0, unsigned short* __restrict__ d1,
                   unsigned short* __restrict__ d2, unsigned short* __restrict__ d3,
                   int n4)
{
  const int i = blockIdx.x * 256 + threadIdx.x;
  if (i >= n4) return;
  const float* s; unsigned short* d;
  switch (blockIdx.y) {
    case 0: s = s0; d = d0; break;
    case 1: s = s1; d = d1; break;
    case 2: s = s2; d = d2; break;
    default: s = s3; d = d3; break;
  }
  const f32x4 v = ((const f32x4*)s)[i];
  u16x4 o;
  o.x = f2bf(v.x); o.y = f2bf(v.y); o.z = f2bf(v.z); o.w = f2bf(v.w);
  ((u16x4*)d)[i] = o;
}

// ---------------------------------------------------------------------------
// 256x128-tile 8-phase GEMM (R4). Same verified schedule as the R3 256^2
// kernel (counted vmcnt, raw s_barrier, setprio, (row>>1)&3 swizzle with 0
// measured bank conflicts) -- geometry changed so every dispatch round is
// full: QKV grid 16x48=768 = 3 exact rounds of 256 CUs; Wo grid 16x16=256
// = 1 exact round. (The 256^2 tile gave 384 blocks = 1.5 rounds -> 75%
// round efficiency; that, not the schedule, capped MfmaUtil at 35%.)
// 512 thr = 8 waves (4M x 2N), wave tile 64x64, BK=64 as two 32-k halves.
// LDS: 2 buf x {A 256x32x2B x2kk = 32K, B 128x32x2B x2kk = 16K} = 96 KiB.
// Uniform phase: {8 ds_read_b128 | stage 3 DMAs (one kk-half of t+1) |
// s_barrier | lgkmcnt(0) | setprio(1) 16 MFMA setprio(0) | vmcnt(3) |
// s_barrier}. vmcnt(3) leaves the just-issued half in flight (never 0).
template<int OUTMODE>
__global__ __launch_bounds__(512, 2)
void gemm_bt9(const __hip_bfloat16* __restrict__ A,
              const __hip_bfloat16* __restrict__ Bw,
              void* __restrict__ C, int M, int N, int K)
{
  extern __shared__ char lds[];
  const int lane = threadIdx.x & 63;
  const int w    = threadIdx.x >> 6;   // 0..7
  const int fr   = lane & 15;
  const int fg   = lane >> 4;          // 0..3

  // XCD-aware swizzle of the linear block id (grid % 8 == 0)
  const int nblk = N >> 7;             // N / 128
  const int cpx  = gridDim.x >> 3;
  const int lin  = blockIdx.x;
  const int swz  = (lin & 7) * cpx + (lin >> 3);
  const int m0 = (swz / nblk) << 8;
  const int n0 = (swz % nblk) << 7;

  // LDS geometry (per 48-KB buffer): A at 0 (kk*16384), B at 32768 (kk*8192);
  // row stride 64 B; 16B-slot ^= (row>>1)&3  (row parity x 4 slots = 8 bank
  // windows, each hit exactly 2x per 16 rows -> conflict-free, measured R4).
  const int Ssw = (fg ^ ((fr >> 1) & 3)) << 4;
  const int pA  = ((w >> 1) * 64 + fr) * 64 + Ssw;          // + mi*1024 + kk*16384
  const int pB  = 32768 + ((w & 1) * 64 + fr) * 64 + Ssw;   // + nj*1024 + kk*8192

  // Staging: per kk-half, 3 x 8KB units (A rows 0-127, A rows 128-255, B rows
  // 0-127); each thread 1 DMA per unit. Dest row = w*16 + lane>>2 (+128 for A
  // unit 1), dest slot = lane&3 (linear in lane -> valid global_load_lds).
  // Source k-group pre-swizzled: (lane&3) ^ ((row>>1)&3) = (lane&3)^((lane>>3)&3).
  const int srow = w * 16 + (lane >> 2);               // 0..127
  const int ks   = ((lane & 3) ^ ((lane >> 3) & 3)) * 8;
  const __hip_bfloat16* Asrc = A  + (size_t)(m0 + srow) * K + ks;
  const __hip_bfloat16* Bsrc = Bw + (size_t)(n0 + srow) * K + ks;
  const int dstA = srow * 64 + (lane & 3) * 16;        // < 8192

#define STG(NB, KH, KT) do {                                                   \
    const size_t ko_ = (size_t)(KT)*64 + (KH)*32;                              \
    async_load16(Asrc + ko_,                                                   \
                 lds + (NB)*49152 + (KH)*16384 + dstA);                        \
    async_load16(Asrc + (size_t)128*K + ko_,                                   \
                 lds + (NB)*49152 + (KH)*16384 + 8192 + dstA);                 \
    async_load16(Bsrc + ko_,                                                   \
                 lds + (NB)*49152 + 32768 + (KH)*8192 + dstA);                 \
  } while (0)

#define RD(KK, BB) do {                                                        \
    const char* pa_ = lds + (BB)*49152 + (KK)*16384 + pA;                      \
    aR[0] = *(const bf16x8*)(pa_);        aR[1] = *(const bf16x8*)(pa_ + 1024);\
    aR[2] = *(const bf16x8*)(pa_ + 2048); aR[3] = *(const bf16x8*)(pa_ + 3072);\
    const char* pb_ = lds + (BB)*49152 + (KK)*8192 + pB;                       \
    bR[0] = *(const bf16x8*)(pb_);        bR[1] = *(const bf16x8*)(pb_ + 1024);\
    bR[2] = *(const bf16x8*)(pb_ + 2048); bR[3] = *(const bf16x8*)(pb_ + 3072);\
  } while (0)

#define MFMA16()                                                               \
    _Pragma("unroll")                                                          \
    for (int i_ = 0; i_ < 4; i_++)                                             \
    _Pragma("unroll")                                                          \
    for (int j_ = 0; j_ < 4; j_++)                                             \
      acc[i_][j_] = __builtin_amdgcn_mfma_f32_16x16x32_bf16(                   \
          aR[i_], bR[j_], acc[i_][j_], 0, 0, 0)

#define BARX() __builtin_amdgcn_s_barrier()
#define LGKM0() do { asm volatile("s_waitcnt lgkmcnt(0)" ::: "memory");        \
                     __builtin_amdgcn_sched_barrier(0); } while (0)
#define VMW(NN) asm volatile("s_waitcnt vmcnt(" #NN ")" ::: "memory")
#define PRIO(P) __builtin_amdgcn_s_setprio(P)

  f32x4 acc[4][4];
#pragma unroll
  for (int i = 0; i < 4; i++)
#pragma unroll
    for (int j = 0; j < 4; j++) acc[i][j] = (f32x4)0.0f;

  bf16x8 aR[4], bR[4];

  // prologue: stage both kk-halves of tile 0 into buffer 0
  STG(0, 0, 0);
  STG(0, 1, 0);
  VMW(3);          // kk0(0) resident; kk1(0) still in flight
  BARX();

  const int nk = K >> 6;   // K-tiles of 64

  for (int t = 0; t < nk - 1; ++t) {
    const int bb = t & 1, nb = bb ^ 1;
    // P0: kk=0
    RD(0, bb);
    STG(nb, 0, t + 1);
    BARX(); LGKM0();
    PRIO(1); MFMA16(); PRIO(0);
    VMW(3);        // drain kk1(t) (needed P1); leave kk0(t+1) in flight
    BARX();
    // P1: kk=1
    RD(1, bb);
    STG(nb, 1, t + 1);
    BARX(); LGKM0();
    PRIO(1); MFMA16(); PRIO(0);
    VMW(3);        // drain kk0(t+1) (needed next P0); leave kk1(t+1)
    BARX();
  }
  { // peeled last tile: no staging
    const int bb = (nk - 1) & 1;
    RD(0, bb);
    BARX(); LGKM0();
    PRIO(1); MFMA16(); PRIO(0);
    VMW(0);        // drain kk1(nk-1)
    BARX();
    RD(1, bb);
    BARX(); LGKM0();
    PRIO(1); MFMA16(); PRIO(0);
  }

  // epilogue: direct scattered C write (same fragment->C map as before)
  const int wr = (w >> 1) * 64, wc = (w & 1) * 64;
#pragma unroll
  for (int mi = 0; mi < 4; mi++) {
    const int row = m0 + wr + mi*16 + fg*4;
#pragma unroll
    for (int nj = 0; nj < 4; nj++) {
      const int col = n0 + wc + nj*16 + fr;
#pragma unroll
      for (int r = 0; r < 4; r++) {
        if (OUTMODE == 1) {
          ((float*)C)[(size_t)(row + r)*N + col] = acc[mi][nj][r];
        } else if (OUTMODE == 0) {
          ((unsigned short*)C)[(size_t)(row + r)*N + col] = f2bf(acc[mi][nj][r]);
        } else if (OUTMODE == 2) {
          const int rr = row + r;
          const int b = rr >> 11, s = rr & 2047;
          const int h = col >> 7, d = col & 127;
          ((unsigned short*)C)[(((size_t)(b*H_ + h) << 11) + s)*D_ + d] = f2bf(acc[mi][nj][r]);
        } else {   // OUTMODE == 3: fused QKV, outputs contiguous ELEMS apart
          const int rr = row + r;
          const int b = rr >> 11, s = rr & 2047;
          const int t2 = col >> 11;            // 0=Q 1=K 2=V
          const int h = (col >> 7) & 15, d = col & 127;
          ((unsigned short*)C)[(size_t)t2*ELEMS +
              (((size_t)(b*H_ + h) << 11) + s)*D_ + d] = f2bf(acc[mi][nj][r]);
        }
      }
    }
  }
#undef STG
#undef RD
#undef MFMA16
#undef BARX
#undef LGKM0
#undef VMW
#undef PRIO
}

// xpos rotary, in place on head-major bf16 Q and K [b,h,s,d].
__global__ __launch_bounds__(256)
void xpos_rotary(__hip_bfloat16* __restrict__ Q, __hip_bfloat16* __restrict__ Kt)
{
  const int idx = blockIdx.x * 256 + threadIdx.x;   // [0, B*H*S*64)
  const int j = idx & 63;
  const int s = (idx >> 6) & 2047;
  const float seq = (float)(s - 1024) * (1.0f/512.0f);
  const float dr = 2.0f + 2.0f*(float)j;
  const float theta = expf(dr * (1.0f/128.0f) * -9.210340371976184f);
  const float zeta  = (dr * (1.0f/64.0f) + 51.2f) * (1.0f/52.2f);
  const float ang = seq * theta;
  const float c  = cosf(ang);
  const float sn = sinf(ang);
  const float t  = expf(seq * logf(zeta));
  const float it = 1.0f / t;

  const size_t base = (size_t)(idx >> 6) * 128 + 2*j;
  unsigned short* Qs = (unsigned short*)Q;
  unsigned short* Ks = (unsigned short*)Kt;
  const float q0 = __bfloat162float(Q[base]),  q1 = __bfloat162float(Q[base+1]);
  Qs[base]   = f2bf((q0*c - q1*sn) * t);
  Qs[base+1] = f2bf((q1*c + q0*sn) * t);
  const float k0 = __bfloat162float(Kt[base]), k1 = __bfloat162float(Kt[base+1]);
  Ks[base]   = f2bf((k0*c - k1*sn) * it);
  Ks[base+1] = f2bf((k1*c + k0*sn) * it);
}

// Vh [b,h,s,d] bf16 -> VT3 packed f16:
// per (bh, kt=s/64) 16-KB tile, inner offset = d*64 + g*16 + half*8 + s1*4 + r
// where key=s%64 = (half*2+s1)*16 + g*4 + r.
__global__ __launch_bounds__(256)
void transpose_v(const __hip_bfloat16* __restrict__ Vh, _Float16* __restrict__ VT3)
{
  __shared__ float tile[32][33];
  const int tx = threadIdx.x, ty = threadIdx.y;      // block (32, 8)
  const int bh = blockIdx.z;
  const int s0 = blockIdx.x * 32, d0 = blockIdx.y * 32;
  const int kt = s0 >> 6, koff = s0 & 63;
#pragma unroll
  for (int r = 0; r < 4; r++) {
    const int s = s0 + ty + r*8;
    tile[ty + r*8][tx] = __bfloat162float(Vh[((size_t)bh*S_ + s)*D_ + d0 + tx]);
  }
  __syncthreads();
  const int key = koff + tx;
  const int g = (key >> 2) & 3, rr = key & 3, half = (key >> 5) & 1, s1 = (key >> 4) & 1;
  const size_t base = (size_t)bh*S_*D_ + (size_t)kt*8192 + g*16 + half*8 + s1*4 + rr;
#pragma unroll
  for (int r = 0; r < 4; r++) {
    const int d = d0 + ty + r*8;
    VT3[base + d*64] = (_Float16)tile[tx][ty + r*8];
  }
}

// Flash attention, causal (R1 structure: LDS-staged K/V via global_load_lds,
// 32-key double-buffered tiles shared by all 4 waves).
__global__ __launch_bounds__(256, 2)
void attn_fwd(const __hip_bfloat16* __restrict__ Qh,
              const __hip_bfloat16* __restrict__ Kh,
              const _Float16* __restrict__ VT3,
              __hip_bfloat16* __restrict__ O)
{
  __shared__ union {
    struct { unsigned short Kt[2][4096]; _Float16 Vt[2][4096]; } st;
    float ep[64*132];
  } sh;

  const int lane = threadIdx.x & 63;
  const int w    = threadIdx.x >> 6;
  const int L  = blockIdx.x;                   // 0..1023
  const int bh = (L & 7) + 8*((L >> 3) & 3);   // bh pinned to XCD = bh&7
  const int x  = 31 - (L >> 5);                // longest-first
  const int b = bh >> 4, h = bh & 15;
  const int q0 = x*64 + w*16;
  const int qc = lane & 15;
  const int g  = lane >> 4;
  const int qv = q0 + qc;

  const __hip_bfloat16* Kb = Kh + (size_t)bh*S_*D_;
  const _Float16* vtb = VT3 + (size_t)bh*S_*D_;

  const int kswz  = (qc & 7) << 4;                     // K read swizzle (bytes)
  const int vbase = qc*64 + ((g ^ ((qc >> 1) & 3)) << 4);  // V read base (bytes)

#define STAGE(BUF, P) do {                                                       \
    const int kb0_ = (P)*32;                                                     \
    _Pragma("unroll")                                                            \
    for (int ii = 0; ii < 2; ii++) {                                             \
      const int chunk = w*2 + ii;                                                \
      const int key   = chunk*4 + (lane >> 4);                                   \
      const int srcin = ((lane & 15)*16) ^ ((key & 7) << 4);                     \
      async_load16((const char*)Kb + (size_t)(kb0_ + key)*256 + srcin,           \
                   (char*)sh.st.Kt[BUF] + chunk*1024);                           \
    }                                                                            \
    const int kt_ = (P) >> 1, h_ = (P) & 1;                                      \
    _Pragma("unroll")                                                            \
    for (int ii = 0; ii < 2; ii++) {                                             \
      const int chunk = w*2 + ii;                                                \
      const int dd = chunk*16 + (lane >> 2);                                     \
      const int gg = (lane & 3) ^ ((lane >> 3) & 3);                             \
      async_load16((const char*)vtb + ((size_t)kt_*8192 + dd*64 + gg*16 + h_*8)*2,\
                   (char*)sh.st.Vt[BUF] + chunk*1024);                           \
    }                                                                            \
  } while (0)

#define COMPUTE(BUF, P) do {                                                     \
    const int k0_ = (P)*32;                                                      \
    const char* Kl = (const char*)sh.st.Kt[BUF];                                 \
    const char* Vl = (const char*)sh.st.Vt[BUF];                                 \
    bf16x8 ka[4], kbb[4]; f16x8 vv[8];                                           \
    _Pragma("unroll")                                                            \
    for (int c = 0; c < 4; c++) {                                                \
      const int off = (c*64 + g*16) ^ kswz;                                      \
      ka[c]  = *(const bf16x8*)(Kl + qc*256 + off);                              \
      kbb[c] = *(const bf16x8*)(Kl + (16 + qc)*256 + off);                       \
    }                                                                            \
    _Pragma("unroll")                                                            \
    for (int t = 0; t < 8; t++) vv[t] = *(const f16x8*)(Vl + t*1024 + vbase);    \
    f32x4 sA = (f32x4)0.0f, sB = (f32x4)0.0f;                                    \
    _Pragma("unroll")                                                            \
    for (int c = 0; c < 4; c++) {                                                \
      sA = __builtin_amdgcn_mfma_f32_16x16x32_bf16(ka[c],  qf[c], sA, 0, 0, 0);  \
      sB = __builtin_amdgcn_mfma_f32_16x16x32_bf16(kbb[c], qf[c], sB, 0, 0, 0);  \
    }                                                                            \
    float sv[8];                                                                 \
    _Pragma("unroll")                                                            \
    for (int r = 0; r < 4; r++) {                                                \
      sv[r]   = (k0_      + g*4 + r <= qv) ? sA[r]*scale : -1e30f;               \
      sv[4+r] = (k0_ + 16 + g*4 + r <= qv) ? sB[r]*scale : -1e30f;               \
    }                                                                            \
    float mx = sv[0];                                                            \
    _Pragma("unroll")                                                            \
    for (int j = 1; j < 8; j++) mx = fmaxf(mx, sv[j]);                           \
    mx = fmaxf(mx, __shfl_xor(mx, 16));                                          \
    mx = fmaxf(mx, __shfl_xor(mx, 32));                                          \
    const float m_new = fmaxf(m_i, mx);                                          \
    const float alpha = __expf(m_i - m_new);                                     \
    float p[8], ps = 0.0f;                                                       \
    _Pragma("unroll")                                                            \
    for (int j = 0; j < 8; j++) { p[j] = __expf(sv[j] - m_new); ps += p[j]; }    \
    ps += __shfl_xor(ps, 16);                                                    \
    ps += __shfl_xor(ps, 32);                                                    \
    l_i = l_i*alpha + ps;                                                        \
    m_i = m_new;                                                                 \
    f16x4 pA, pB;                                                                \
    _Pragma("unroll")                                                            \
    for (int r = 0; r < 4; r++) { pA[r] = (_Float16)p[r]; pB[r] = (_Float16)p[4+r]; } \
    _Pragma("unroll")                                                            \
    for (int t = 0; t < 8; t++) acc_o[t] *= alpha;                               \
    _Pragma("unroll")                                                            \
    for (int t = 0; t < 8; t++) {                                                \
      const f16x4 vA = __builtin_shufflevector(vv[t], vv[t], 0, 1, 2, 3);        \
      const f16x4 vB = __builtin_shufflevector(vv[t], vv[t], 4, 5, 6, 7);        \
      acc_o[t] = __builtin_amdgcn_mfma_f32_16x16x16f16(vA, pA, acc_o[t], 0, 0, 0); \
      acc_o[t] = __builtin_amdgcn_mfma_f32_16x16x16f16(vB, pB, acc_o[t], 0, 0, 0); \
    }                                                                            \
  } while (0)

  // issue tile-0 DMA first so it flies under the Q register loads
  STAGE(0, 0);

  bf16x8 qf[4];
  {
    const __hip_bfloat16* qrow = Qh + ((size_t)bh*S_ + qv)*D_ + g*8;
#pragma unroll
    for (int c = 0; c < 4; c++) qf[c] = *(const bf16x8*)(qrow + c*32);
  }

  f32x4 acc_o[8];
#pragma unroll
  for (int t = 0; t < 8; t++) acc_o[t] = (f32x4)0.0f;
  float m_i = -1e30f, l_i = 0.0f;
  const float scale = 0.08838834764831845f;   // 1/sqrt(128)

  const int ntile = 2*x + 2;       // 32-key tiles, uniform across the block

  __syncthreads();                 // drains vmcnt(0): tile 0 resident

  for (int p = 0; p < ntile; ++p) {
    if (p + 1 < ntile) STAGE((p + 1) & 1, p + 1);   // async prefetch
    COMPUTE(p & 1, p);
    __syncthreads();               // drain: tile p+1 resident, buf p free
  }

  // epilogue: O^T[d][q] -> LDS as O[q][d] (stride 132), coalesced bf16 store.
  const float inv_l = 1.0f / l_i;
#pragma unroll
  for (int t = 0; t < 8; t++)
#pragma unroll
    for (int r = 0; r < 4; r++)
      sh.ep[(w*16 + qc)*132 + t*16 + g*4 + r] = acc_o[t][r] * inv_l;
  __syncthreads();

  const int row = threadIdx.x >> 2;          // 0..63
  const int c0  = (threadIdx.x & 3) * 32;
  unsigned short* Os = (unsigned short*)O;
  const size_t obase = ((size_t)b*S_ + x*64 + row)*E_ + h*D_;
#pragma unroll
  for (int i = 0; i < 8; i++) {
    const f32x4 v4 = *(const f32x4*)(sh.ep + row*132 + c0 + i*4);
    u16x4 o4;
    o4.x = f2bf(v4.x); o4.y = f2bf(v4.y); o4.z = f2bf(v4.z); o4.w = f2bf(v4.w);
    *(u16x4*)(Os + obase + c0 + i*4) = o4;
  }
#undef STAGE
#undef COMPUTE
}

extern "C" void kernel_launch(void* const* d_in, const int* in_sizes, int n_in,
                              void* d_out, int out_size, void* d_ws, size_t ws_size,
                              hipStream_t stream)
{
  (void)in_sizes; (void)n_in; (void)out_size; (void)ws_size;
  const float* act = (const float*)d_in[0];
  const float* Wq  = (const float*)d_in[1];
  const float* Wk  = (const float*)d_in[2];
  const float* Wv  = (const float*)d_in[3];
  const float* Wo  = (const float*)d_in[4];

  __hip_bfloat16* actb = (__hip_bfloat16*)d_ws;
  __hip_bfloat16* Wqb  = actb + ELEMS;
  __hip_bfloat16* Wkb  = Wqb + WELEMS;
  __hip_bfloat16* Wvb  = Wkb + WELEMS;
  __hip_bfloat16* Wob  = Wvb + WELEMS;
  __hip_bfloat16* Q    = Wob + WELEMS;
  __hip_bfloat16* Kp   = Q + ELEMS;
  __hip_bfloat16* V    = Kp + ELEMS;
  _Float16*       VT   = (_Float16*)(V + ELEMS);
  __hip_bfloat16* AO   = V;   // V dead after transpose_v; reuse for attn output

  cvt_f32_bf16<<<ELEMS/4/256, 256, 0, stream>>>(act, (unsigned short*)actb, ELEMS/4);
  cvt4_f32_bf16<<<dim3(WELEMS/4/256, 4), 256, 0, stream>>>(
      Wq, Wk, Wv, Wo,
      (unsigned short*)Wqb, (unsigned short*)Wkb,
      (unsigned short*)Wvb, (unsigned short*)Wob, WELEMS/4);

  // Fused QKV projection: [4096 x 6144 x 2048] on the 256x128 8-phase kernel;
  // grid = 16*48 = 768 = 3 exact rounds of 256 CUs (%8==0 for XCD swizzle).
  gemm_bt9<3><<<(B_*S_/256)*(3*E_/128), 512, 98304, stream>>>(
      actb, Wqb, Q, B_*S_, 3*E_, E_);

  xpos_rotary<<<(B_*S_*H_*64)/256, 256, 0, stream>>>(Q, Kp);
  transpose_v<<<dim3(S_/32, D_/32, B_*H_), dim3(32, 8), 0, stream>>>(V, VT);
  attn_fwd<<<1024, 256, 0, stream>>>(Q, Kp, VT, AO);

  // Wo projection: [4096 x 2048 x 2048], grid 16*16 = 256 = 1 exact round.
  gemm_bt9<1><<<(B_*S_/256)*(E_/128), 512, 98304, stream>>>(
      AO, Wob, d_out, B_*S_, E_, E_);
}